// Round 1
// baseline (372.242 us; speedup 1.0000x reference)
//
#include <hip/hip_runtime.h>
#include <hip/hip_bf16.h>
#include <cstdint>
#include <cstddef>

#define B_ 2
#define T_ 2048
#define NH 16
#define NKV 4
#define DH 128
#define DM 2048
#define WIN 512

typedef __attribute__((ext_vector_type(4))) float f32x4;
typedef __attribute__((ext_vector_type(8))) __bf16 bf16x8;
typedef __attribute__((ext_vector_type(8))) short s16x8;

using bf16 = __hip_bfloat16;

__device__ inline void gload_lds16(const void* g, void* l) {
  __builtin_amdgcn_global_load_lds(
      (const __attribute__((address_space(1))) void*)g,
      (__attribute__((address_space(3))) void*)l, 16, 0, 0);
}

// ---------------- fp32 -> bf16 convert ----------------
__global__ void k_f32_to_bf16(const float* __restrict__ in, bf16* __restrict__ out, int n) {
  int i = (blockIdx.x * blockDim.x + threadIdx.x) * 4;
  if (i >= n) return;
  float4 v = *(const float4*)(in + i);
  out[i + 0] = __float2bfloat16(v.x);
  out[i + 1] = __float2bfloat16(v.y);
  out[i + 2] = __float2bfloat16(v.z);
  out[i + 3] = __float2bfloat16(v.w);
}

// ---------------- W (K x N fp32) -> Wt (N x K bf16) ----------------
__global__ __launch_bounds__(256) void k_transpose_bf16(const float* __restrict__ W,
                                                        bf16* __restrict__ Wt, int K, int N) {
  __shared__ float tile[64][65];
  int n0 = blockIdx.x * 64, k0 = blockIdx.y * 64;
  int tx = threadIdx.x & 63, tg = threadIdx.x >> 6;
#pragma unroll
  for (int r = 0; r < 16; ++r) {
    int k = tg * 16 + r;
    tile[k][tx] = W[(size_t)(k0 + k) * N + n0 + tx];
  }
  __syncthreads();
#pragma unroll
  for (int r = 0; r < 16; ++r) {
    int nn = tg * 16 + r;
    Wt[(size_t)(n0 + nn) * K + k0 + tx] = __float2bfloat16(tile[tx][nn]);
  }
}

// ---------------- GEMM: C[M][N] = A[M][K] * Bt[N][K]^T ----------------
template <bool OUT_BF16>
__global__ __launch_bounds__(256) void k_gemm_bt(const bf16* __restrict__ A,
                                                 const bf16* __restrict__ Bt,
                                                 void* __restrict__ Cout,
                                                 int M, int N, int K) {
  __shared__ bf16 As[128 * 32];
  __shared__ bf16 Bs[128 * 32];
  const int lane = threadIdx.x & 63;
  const int w = threadIdx.x >> 6;
  const int wr = w >> 1, wc = w & 1;
  const int li = lane & 15, g = lane >> 4;
  const int m0 = blockIdx.y * 128, n0 = blockIdx.x * 128;
  const int lrow = lane >> 2;     // 0..15
  const int lk = (lane & 3) * 8;  // 0,8,16,24

  f32x4 acc[4][4] = {};

  for (int k0 = 0; k0 < K; k0 += 32) {
#pragma unroll
    for (int it = 0; it < 2; ++it) {
      int c = w * 2 + it;
      const bf16* ga = A + (size_t)(m0 + c * 16 + lrow) * K + k0 + lk;
      gload_lds16(ga, &As[c * 512]);
      const bf16* gb = Bt + (size_t)(n0 + c * 16 + lrow) * K + k0 + lk;
      gload_lds16(gb, &Bs[c * 512]);
    }
    __syncthreads();

    bf16x8 af[4], bfr[4];
#pragma unroll
    for (int m = 0; m < 4; ++m)
      af[m] = *(const bf16x8*)&As[(wr * 64 + m * 16 + li) * 32 + g * 8];
#pragma unroll
    for (int n = 0; n < 4; ++n)
      bfr[n] = *(const bf16x8*)&Bs[(wc * 64 + n * 16 + li) * 32 + g * 8];
#pragma unroll
    for (int m = 0; m < 4; ++m)
#pragma unroll
      for (int n = 0; n < 4; ++n)
        acc[m][n] = __builtin_amdgcn_mfma_f32_16x16x32_bf16(af[m], bfr[n], acc[m][n], 0, 0, 0);
    __syncthreads();
  }

#pragma unroll
  for (int m = 0; m < 4; ++m)
#pragma unroll
    for (int n = 0; n < 4; ++n)
#pragma unroll
      for (int r = 0; r < 4; ++r) {
        int row = m0 + wr * 64 + m * 16 + g * 4 + r;
        int col = n0 + wc * 64 + n * 16 + li;
        float v = acc[m][n][r];
        if (OUT_BF16)
          ((bf16*)Cout)[(size_t)row * N + col] = __float2bfloat16(v);
        else
          ((float*)Cout)[(size_t)row * N + col] = v;
      }
}

// ---------------- RoPE (in place, bf16) ----------------
__global__ void k_rope(bf16* __restrict__ X, const float* __restrict__ cosT,
                       const float* __restrict__ sinT, int nheads, int total) {
  int p = blockIdx.x * blockDim.x + threadIdx.x;
  if (p >= total) return;
  int i = p & 63;
  int h = (p >> 6) % nheads;
  int bt = p / (64 * nheads);
  int t = bt & (T_ - 1);
  float c = cosT[t * 64 + i], s = sinT[t * 64 + i];
  size_t base = ((size_t)bt * nheads + h) * DH + 2 * i;
  float tr = __bfloat162float(X[base]);
  float ti = __bfloat162float(X[base + 1]);
  X[base] = __float2bfloat16(tr * c - ti * s);
  X[base + 1] = __float2bfloat16(tr * s + ti * c);
}

// ---------------- windowed flash attention ----------------
// grid: (T/16, B*NH), block: 64 (1 wave). Each wave: 16 q-rows.
__global__ __launch_bounds__(64) void k_attn(const bf16* __restrict__ Q,
                                             const bf16* __restrict__ Kb,
                                             const bf16* __restrict__ Vb,
                                             bf16* __restrict__ Y) {
  __shared__ bf16 Plds[16 * 32];
  const int lane = threadIdx.x;
  const int li = lane & 15, g = lane >> 4;
  const int t0 = blockIdx.x * 16;
  const int bh = blockIdx.y;
  const int b = bh / NH, h = bh % NH, kvh = h / (NH / NKV);

  bf16x8 qf[4];
  const bf16* qbase = Q + ((size_t)(b * T_ + t0 + li) * NH + h) * DH;
#pragma unroll
  for (int dk = 0; dk < 4; ++dk) qf[dk] = *(const bf16x8*)(qbase + dk * 32 + g * 8);

  float mrow[4] = {-1e30f, -1e30f, -1e30f, -1e30f};
  float srow[4] = {0.f, 0.f, 0.f, 0.f};
  f32x4 acc[8] = {};

  const float scale = 0.08838834764831845f;  // 1/sqrt(128)

  int ks = t0 - (WIN - 1);
  if (ks < 0) ks = 0;
  ks &= ~31;
  const int kend = t0 + 15;

  for (int kt = ks; kt <= kend; kt += 32) {
    f32x4 s[2] = {};
#pragma unroll
    for (int n = 0; n < 2; ++n) {
      const bf16* kbase = Kb + ((size_t)(b * T_ + kt + n * 16 + li) * NKV + kvh) * DH;
#pragma unroll
      for (int dk = 0; dk < 4; ++dk) {
        bf16x8 kf = *(const bf16x8*)(kbase + dk * 32 + g * 8);
        s[n] = __builtin_amdgcn_mfma_f32_16x16x32_bf16(qf[dk], kf, s[n], 0, 0, 0);
      }
    }

    float p[2][4], tmax[4];
#pragma unroll
    for (int r = 0; r < 4; ++r) {
      int t = t0 + g * 4 + r;
#pragma unroll
      for (int n = 0; n < 2; ++n) {
        int key = kt + n * 16 + li;
        bool valid = (key <= t) && (key >= t - (WIN - 1));
        p[n][r] = valid ? s[n][r] * scale : -1e30f;
      }
      tmax[r] = fmaxf(p[0][r], p[1][r]);
    }
#pragma unroll
    for (int mk = 1; mk < 16; mk <<= 1)
#pragma unroll
      for (int r = 0; r < 4; ++r) tmax[r] = fmaxf(tmax[r], __shfl_xor(tmax[r], mk));

    float alpha[4], rs[4];
#pragma unroll
    for (int r = 0; r < 4; ++r) {
      float nm = fmaxf(mrow[r], tmax[r]);
      alpha[r] = __expf(mrow[r] - nm);
      mrow[r] = nm;
#pragma unroll
      for (int n = 0; n < 2; ++n)
        p[n][r] = (p[n][r] <= -1e29f) ? 0.f : __expf(p[n][r] - nm);
      rs[r] = p[0][r] + p[1][r];
    }
#pragma unroll
    for (int mk = 1; mk < 16; mk <<= 1)
#pragma unroll
      for (int r = 0; r < 4; ++r) rs[r] += __shfl_xor(rs[r], mk);
#pragma unroll
    for (int r = 0; r < 4; ++r) srow[r] = srow[r] * alpha[r] + rs[r];
#pragma unroll
    for (int db = 0; db < 8; ++db)
#pragma unroll
      for (int r = 0; r < 4; ++r) acc[db][r] *= alpha[r];

    __syncthreads();
#pragma unroll
    for (int r = 0; r < 4; ++r)
#pragma unroll
      for (int n = 0; n < 2; ++n)
        Plds[(g * 4 + r) * 32 + n * 16 + li] = __float2bfloat16(p[n][r]);
    __syncthreads();

    bf16x8 pf = *(const bf16x8*)&Plds[li * 32 + g * 8];
    const short* vsrc = (const short*)(Vb + ((size_t)(b * T_ + kt + g * 8) * NKV + kvh) * DH);
#pragma unroll
    for (int db = 0; db < 8; ++db) {
      s16x8 vs;
#pragma unroll
      for (int j = 0; j < 8; ++j) vs[j] = vsrc[(size_t)j * NKV * DH + db * 16 + li];
      acc[db] = __builtin_amdgcn_mfma_f32_16x16x32_bf16(pf, __builtin_bit_cast(bf16x8, vs),
                                                        acc[db], 0, 0, 0);
    }
  }

  bf16* ybase = Y + ((size_t)(b * T_ + t0 + g * 4) * NH + h) * DH;
#pragma unroll
  for (int r = 0; r < 4; ++r) {
    float inv = 1.f / srow[r];
#pragma unroll
    for (int db = 0; db < 8; ++db)
      ybase[(size_t)r * NH * DH + db * 16 + li] = __float2bfloat16(acc[db][r] * inv);
  }
}

extern "C" void kernel_launch(void* const* d_in, const int* in_sizes, int n_in,
                              void* d_out, int out_size, void* d_ws, size_t ws_size,
                              hipStream_t stream) {
  const float* x = (const float*)d_in[0];
  const float* cosT = (const float*)d_in[1];
  const float* sinT = (const float*)d_in[2];
  const float* Wq = (const float*)d_in[3];
  const float* Wk = (const float*)d_in[4];
  const float* Wv = (const float*)d_in[5];
  const float* Wo = (const float*)d_in[6];
  float* out = (float*)d_out;

  char* ws = (char*)d_ws;
  bf16* xb = (bf16*)ws;   ws += (size_t)4096 * 2048 * 2;   // 16 MB (reused as yb)
  bf16* Wqt = (bf16*)ws;  ws += (size_t)2048 * 2048 * 2;   // 8 MB
  bf16* Wkt = (bf16*)ws;  ws += (size_t)512 * 2048 * 2;    // 2 MB
  bf16* Wvt = (bf16*)ws;  ws += (size_t)512 * 2048 * 2;    // 2 MB
  bf16* Wot = (bf16*)ws;  ws += (size_t)2048 * 2048 * 2;   // 8 MB
  bf16* qb = (bf16*)ws;   ws += (size_t)4096 * 2048 * 2;   // 16 MB
  bf16* kb = (bf16*)ws;   ws += (size_t)4096 * 512 * 2;    // 4 MB
  bf16* vb = (bf16*)ws;   ws += (size_t)4096 * 512 * 2;    // 4 MB
  bf16* yb = xb;  // xb dead after QKV GEMMs

  k_f32_to_bf16<<<(4096 * 2048 / 4 + 255) / 256, 256, 0, stream>>>(x, xb, 4096 * 2048);
  k_transpose_bf16<<<dim3(2048 / 64, 2048 / 64), 256, 0, stream>>>(Wq, Wqt, 2048, 2048);
  k_transpose_bf16<<<dim3(512 / 64, 2048 / 64), 256, 0, stream>>>(Wk, Wkt, 2048, 512);
  k_transpose_bf16<<<dim3(512 / 64, 2048 / 64), 256, 0, stream>>>(Wv, Wvt, 2048, 512);
  k_transpose_bf16<<<dim3(2048 / 64, 2048 / 64), 256, 0, stream>>>(Wo, Wot, 2048, 2048);

  k_gemm_bt<true><<<dim3(2048 / 128, 4096 / 128), 256, 0, stream>>>(xb, Wqt, qb, 4096, 2048, 2048);
  k_gemm_bt<true><<<dim3(512 / 128, 4096 / 128), 256, 0, stream>>>(xb, Wkt, kb, 4096, 512, 2048);
  k_gemm_bt<true><<<dim3(512 / 128, 4096 / 128), 256, 0, stream>>>(xb, Wvt, vb, 4096, 512, 2048);

  k_rope<<<(B_ * T_ * NH * 64) / 256, 256, 0, stream>>>(qb, cosT, sinT, NH, B_ * T_ * NH * 64);
  k_rope<<<(B_ * T_ * NKV * 64) / 256, 256, 0, stream>>>(kb, cosT, sinT, NKV, B_ * T_ * NKV * 64);

  k_attn<<<dim3(T_ / 16, B_ * NH), 64, 0, stream>>>(qb, kb, vb, yb);

  k_gemm_bt<false><<<dim3(2048 / 128, 4096 / 128), 256, 0, stream>>>(yb, Wot, out, 4096, 2048, 2048);
}

// Round 2
// 363.240 us; speedup vs baseline: 1.0248x; 1.0248x over previous
//
#include <hip/hip_runtime.h>
#include <hip/hip_bf16.h>
#include <cstdint>
#include <cstddef>

#define B_ 2
#define T_ 2048
#define NH 16
#define NKV 4
#define DH 128
#define DM 2048
#define WIN 512

typedef __attribute__((ext_vector_type(4))) float f32x4;
typedef __attribute__((ext_vector_type(8))) __bf16 bf16x8;

using bf16 = __hip_bfloat16;

__device__ inline void gload_lds16(const void* g, void* l) {
  __builtin_amdgcn_global_load_lds(
      (const __attribute__((address_space(1))) void*)g,
      (__attribute__((address_space(3))) void*)l, 16, 0, 0);
}

// ---------------- fp32 -> bf16 convert ----------------
__global__ void k_f32_to_bf16(const float* __restrict__ in, bf16* __restrict__ out, int n) {
  int i = (blockIdx.x * blockDim.x + threadIdx.x) * 4;
  if (i >= n) return;
  float4 v = *(const float4*)(in + i);
  out[i + 0] = __float2bfloat16(v.x);
  out[i + 1] = __float2bfloat16(v.y);
  out[i + 2] = __float2bfloat16(v.z);
  out[i + 3] = __float2bfloat16(v.w);
}

// ---------------- W (K x N fp32) -> Wt (N x K bf16) ----------------
__global__ __launch_bounds__(256) void k_transpose_bf16(const float* __restrict__ W,
                                                        bf16* __restrict__ Wt, int K, int N) {
  __shared__ float tile[64][65];
  int n0 = blockIdx.x * 64, k0 = blockIdx.y * 64;
  int tx = threadIdx.x & 63, tg = threadIdx.x >> 6;
#pragma unroll
  for (int r = 0; r < 16; ++r) {
    int k = tg * 16 + r;
    tile[k][tx] = W[(size_t)(k0 + k) * N + n0 + tx];
  }
  __syncthreads();
#pragma unroll
  for (int r = 0; r < 16; ++r) {
    int nn = tg * 16 + r;
    Wt[(size_t)(n0 + nn) * K + k0 + tx] = __float2bfloat16(tile[tx][nn]);
  }
}

// ---------------- GEMM: C[M][N] = A[M][K] * Bt[N][K]^T ----------------
template <bool OUT_BF16>
__global__ __launch_bounds__(256) void k_gemm_bt(const bf16* __restrict__ A,
                                                 const bf16* __restrict__ Bt,
                                                 void* __restrict__ Cout,
                                                 int M, int N, int K) {
  __shared__ bf16 As[128 * 32];
  __shared__ bf16 Bs[128 * 32];
  const int lane = threadIdx.x & 63;
  const int w = threadIdx.x >> 6;
  const int wr = w >> 1, wc = w & 1;
  const int li = lane & 15, g = lane >> 4;
  const int m0 = blockIdx.y * 128, n0 = blockIdx.x * 128;
  const int lrow = lane >> 2;     // 0..15
  const int lk = (lane & 3) * 8;  // 0,8,16,24

  f32x4 acc[4][4] = {};

  for (int k0 = 0; k0 < K; k0 += 32) {
#pragma unroll
    for (int it = 0; it < 2; ++it) {
      int c = w * 2 + it;
      const bf16* ga = A + (size_t)(m0 + c * 16 + lrow) * K + k0 + lk;
      gload_lds16(ga, &As[c * 512]);
      const bf16* gb = Bt + (size_t)(n0 + c * 16 + lrow) * K + k0 + lk;
      gload_lds16(gb, &Bs[c * 512]);
    }
    __syncthreads();

    bf16x8 af[4], bfr[4];
#pragma unroll
    for (int m = 0; m < 4; ++m)
      af[m] = *(const bf16x8*)&As[(wr * 64 + m * 16 + li) * 32 + g * 8];
#pragma unroll
    for (int n = 0; n < 4; ++n)
      bfr[n] = *(const bf16x8*)&Bs[(wc * 64 + n * 16 + li) * 32 + g * 8];
#pragma unroll
    for (int m = 0; m < 4; ++m)
#pragma unroll
      for (int n = 0; n < 4; ++n)
        acc[m][n] = __builtin_amdgcn_mfma_f32_16x16x32_bf16(af[m], bfr[n], acc[m][n], 0, 0, 0);
    __syncthreads();
  }

#pragma unroll
  for (int m = 0; m < 4; ++m)
#pragma unroll
    for (int n = 0; n < 4; ++n)
#pragma unroll
      for (int r = 0; r < 4; ++r) {
        int row = m0 + wr * 64 + m * 16 + g * 4 + r;
        int col = n0 + wc * 64 + n * 16 + li;
        float v = acc[m][n][r];
        if (OUT_BF16)
          ((bf16*)Cout)[(size_t)row * N + col] = __float2bfloat16(v);
        else
          ((float*)Cout)[(size_t)row * N + col] = v;
      }
}

// ---------------- RoPE (in place, bf16) ----------------
__global__ void k_rope(bf16* __restrict__ X, const float* __restrict__ cosT,
                       const float* __restrict__ sinT, int nheads, int total) {
  int p = blockIdx.x * blockDim.x + threadIdx.x;
  if (p >= total) return;
  int i = p & 63;
  int h = (p >> 6) % nheads;
  int bt = p / (64 * nheads);
  int t = bt & (T_ - 1);
  float c = cosT[t * 64 + i], s = sinT[t * 64 + i];
  size_t base = ((size_t)bt * nheads + h) * DH + 2 * i;
  float tr = __bfloat162float(X[base]);
  float ti = __bfloat162float(X[base + 1]);
  X[base] = __float2bfloat16(tr * c - ti * s);
  X[base + 1] = __float2bfloat16(tr * s + ti * c);
}

// ---------------- windowed flash attention ----------------
// grid: (T/64, B*NH), block: 256 (4 independent waves; wave w owns q rows
// t0+w*16 .. t0+w*16+15). No barriers: waves have divergent key-loop trip
// counts (window start differs per wave) and share no LDS.
// V is consumed from VT [NKV*DH][B*T] so PV B-fragments are contiguous 16B.
__global__ __launch_bounds__(256) void k_attn(const bf16* __restrict__ Q,
                                              const bf16* __restrict__ Kb,
                                              const bf16* __restrict__ VT,
                                              bf16* __restrict__ Y) {
  __shared__ bf16 Plds[4][16 * 32];
  const int lane = threadIdx.x & 63;
  const int w = threadIdx.x >> 6;
  const int li = lane & 15, g = lane >> 4;
  const int t0 = blockIdx.x * 64 + w * 16;
  const int bh = blockIdx.y;
  const int b = bh / NH, h = bh % NH, kvh = h / (NH / NKV);

  bf16x8 qf[4];
  const bf16* qbase = Q + ((size_t)(b * T_ + t0 + li) * NH + h) * DH;
#pragma unroll
  for (int dk = 0; dk < 4; ++dk) qf[dk] = *(const bf16x8*)(qbase + dk * 32 + g * 8);

  float mrow[4] = {-1e30f, -1e30f, -1e30f, -1e30f};
  float srow[4] = {0.f, 0.f, 0.f, 0.f};
  f32x4 acc[8] = {};

  const float scale = 0.08838834764831845f;  // 1/sqrt(128)

  int ks = t0 - (WIN - 1);
  if (ks < 0) ks = 0;
  ks &= ~31;
  const int kend = t0 + 15;

  // VT row base for this kv-head / batch: VT[(kvh*DH + d)][b*T + t]
  const bf16* vtbase = VT + (size_t)(kvh * DH) * (B_ * T_) + b * T_;

  for (int kt = ks; kt <= kend; kt += 32) {
    f32x4 s[2] = {};
#pragma unroll
    for (int n = 0; n < 2; ++n) {
      const bf16* kbase = Kb + ((size_t)(b * T_ + kt + n * 16 + li) * NKV + kvh) * DH;
#pragma unroll
      for (int dk = 0; dk < 4; ++dk) {
        bf16x8 kf = *(const bf16x8*)(kbase + dk * 32 + g * 8);
        s[n] = __builtin_amdgcn_mfma_f32_16x16x32_bf16(qf[dk], kf, s[n], 0, 0, 0);
      }
    }

    float p[2][4], tmax[4];
#pragma unroll
    for (int r = 0; r < 4; ++r) {
      int t = t0 + g * 4 + r;
#pragma unroll
      for (int n = 0; n < 2; ++n) {
        int key = kt + n * 16 + li;
        bool valid = (key <= t) && (key >= t - (WIN - 1));
        p[n][r] = valid ? s[n][r] * scale : -1e30f;
      }
      tmax[r] = fmaxf(p[0][r], p[1][r]);
    }
#pragma unroll
    for (int mk = 1; mk < 16; mk <<= 1)
#pragma unroll
      for (int r = 0; r < 4; ++r) tmax[r] = fmaxf(tmax[r], __shfl_xor(tmax[r], mk));

    float alpha[4], rs[4];
#pragma unroll
    for (int r = 0; r < 4; ++r) {
      float nm = fmaxf(mrow[r], tmax[r]);
      alpha[r] = __expf(mrow[r] - nm);
      mrow[r] = nm;
#pragma unroll
      for (int n = 0; n < 2; ++n)
        p[n][r] = (p[n][r] <= -1e29f) ? 0.f : __expf(p[n][r] - nm);
      rs[r] = p[0][r] + p[1][r];
    }
#pragma unroll
    for (int mk = 1; mk < 16; mk <<= 1)
#pragma unroll
      for (int r = 0; r < 4; ++r) rs[r] += __shfl_xor(rs[r], mk);
#pragma unroll
    for (int r = 0; r < 4; ++r) srow[r] = srow[r] * alpha[r] + rs[r];
#pragma unroll
    for (int db = 0; db < 8; ++db)
#pragma unroll
      for (int r = 0; r < 4; ++r) acc[db][r] *= alpha[r];

    // P -> LDS (wave-private slice; intra-wave ordering via compiler lgkmcnt)
#pragma unroll
    for (int r = 0; r < 4; ++r)
#pragma unroll
      for (int n = 0; n < 2; ++n)
        Plds[w][(g * 4 + r) * 32 + n * 16 + li] = __float2bfloat16(p[n][r]);

    bf16x8 pf = *(const bf16x8*)&Plds[w][li * 32 + g * 8];
#pragma unroll
    for (int db = 0; db < 8; ++db) {
      // B fragment: V[kt+g*8+j][db*16+li] = VT[kvh*128+db*16+li][b*T+kt+g*8+j]
      bf16x8 vf = *(const bf16x8*)(vtbase + (size_t)(db * 16 + li) * (B_ * T_) + kt + g * 8);
      acc[db] = __builtin_amdgcn_mfma_f32_16x16x32_bf16(pf, vf, acc[db], 0, 0, 0);
    }
  }

  bf16* ybase = Y + ((size_t)(b * T_ + t0 + g * 4) * NH + h) * DH;
#pragma unroll
  for (int r = 0; r < 4; ++r) {
    float inv = 1.f / srow[r];
#pragma unroll
    for (int db = 0; db < 8; ++db)
      ybase[(size_t)r * NH * DH + db * 16 + li] = __float2bfloat16(acc[db][r] * inv);
  }
}

extern "C" void kernel_launch(void* const* d_in, const int* in_sizes, int n_in,
                              void* d_out, int out_size, void* d_ws, size_t ws_size,
                              hipStream_t stream) {
  const float* x = (const float*)d_in[0];
  const float* cosT = (const float*)d_in[1];
  const float* sinT = (const float*)d_in[2];
  const float* Wq = (const float*)d_in[3];
  const float* Wk = (const float*)d_in[4];
  const float* Wv = (const float*)d_in[5];
  const float* Wo = (const float*)d_in[6];
  float* out = (float*)d_out;

  char* ws = (char*)d_ws;
  bf16* xb = (bf16*)ws;   ws += (size_t)4096 * 2048 * 2;   // 16 MB (reused as yb)
  bf16* Wqt = (bf16*)ws;  ws += (size_t)2048 * 2048 * 2;   // 8 MB
  bf16* Wkt = (bf16*)ws;  ws += (size_t)512 * 2048 * 2;    // 2 MB
  bf16* Wvt = (bf16*)ws;  ws += (size_t)512 * 2048 * 2;    // 2 MB
  bf16* Wot = (bf16*)ws;  ws += (size_t)2048 * 2048 * 2;   // 8 MB
  bf16* qb = (bf16*)ws;   ws += (size_t)4096 * 2048 * 2;   // 16 MB
  bf16* kb = (bf16*)ws;   ws += (size_t)4096 * 512 * 2;    // 4 MB
  bf16* vt = (bf16*)ws;   ws += (size_t)512 * 4096 * 2;    // 4 MB  (V^T: [NKV*DH][B*T])
  bf16* yb = xb;  // xb dead after QKV GEMMs

  k_f32_to_bf16<<<(4096 * 2048 / 4 + 255) / 256, 256, 0, stream>>>(x, xb, 4096 * 2048);
  k_transpose_bf16<<<dim3(2048 / 64, 2048 / 64), 256, 0, stream>>>(Wq, Wqt, 2048, 2048);
  k_transpose_bf16<<<dim3(512 / 64, 2048 / 64), 256, 0, stream>>>(Wk, Wkt, 2048, 512);
  k_transpose_bf16<<<dim3(512 / 64, 2048 / 64), 256, 0, stream>>>(Wv, Wvt, 2048, 512);
  k_transpose_bf16<<<dim3(2048 / 64, 2048 / 64), 256, 0, stream>>>(Wo, Wot, 2048, 2048);

  k_gemm_bt<true><<<dim3(2048 / 128, 4096 / 128), 256, 0, stream>>>(xb, Wqt, qb, 4096, 2048, 2048);
  k_gemm_bt<true><<<dim3(512 / 128, 4096 / 128), 256, 0, stream>>>(xb, Wkt, kb, 4096, 512, 2048);
  // V^T = Wvt * xb^T  (same bt-GEMM with operands swapped): vt[n][m] over [512][4096]
  k_gemm_bt<true><<<dim3(4096 / 128, 512 / 128), 256, 0, stream>>>(Wvt, xb, vt, 512, 4096, 2048);

  k_rope<<<(B_ * T_ * NH * 64) / 256, 256, 0, stream>>>(qb, cosT, sinT, NH, B_ * T_ * NH * 64);
  k_rope<<<(B_ * T_ * NKV * 64) / 256, 256, 0, stream>>>(kb, cosT, sinT, NKV, B_ * T_ * NKV * 64);

  k_attn<<<dim3(T_ / 64, B_ * NH), 256, 0, stream>>>(qb, kb, vt, yb);

  k_gemm_bt<false><<<dim3(2048 / 128, 4096 / 128), 256, 0, stream>>>(yb, Wot, out, 4096, 2048, 2048);
}

// Round 3
// 324.313 us; speedup vs baseline: 1.1478x; 1.1200x over previous
//
#include <hip/hip_runtime.h>
#include <hip/hip_bf16.h>
#include <cstdint>
#include <cstddef>

#define B_ 2
#define T_ 2048
#define NH 16
#define NKV 4
#define DH 128
#define DM 2048
#define WIN 512

typedef __attribute__((ext_vector_type(4))) float f32x4;
typedef __attribute__((ext_vector_type(8))) __bf16 bf16x8;

using bf16 = __hip_bfloat16;

__device__ inline void gload_lds16(const void* g, void* l) {
  __builtin_amdgcn_global_load_lds(
      (const __attribute__((address_space(1))) void*)g,
      (__attribute__((address_space(3))) void*)l, 16, 0, 0);
}

// ---------------- fp32 -> bf16 convert ----------------
__global__ void k_f32_to_bf16(const float* __restrict__ in, bf16* __restrict__ out, int n) {
  int i = (blockIdx.x * blockDim.x + threadIdx.x) * 4;
  if (i >= n) return;
  float4 v = *(const float4*)(in + i);
  out[i + 0] = __float2bfloat16(v.x);
  out[i + 1] = __float2bfloat16(v.y);
  out[i + 2] = __float2bfloat16(v.z);
  out[i + 3] = __float2bfloat16(v.w);
}

// ---------------- W (K x N fp32) -> Wt (N x K bf16) ----------------
__global__ __launch_bounds__(256) void k_transpose_bf16(const float* __restrict__ W,
                                                        bf16* __restrict__ Wt, int K, int N) {
  __shared__ float tile[64][65];
  int n0 = blockIdx.x * 64, k0 = blockIdx.y * 64;
  int tx = threadIdx.x & 63, tg = threadIdx.x >> 6;
#pragma unroll
  for (int r = 0; r < 16; ++r) {
    int k = tg * 16 + r;
    tile[k][tx] = W[(size_t)(k0 + k) * N + n0 + tx];
  }
  __syncthreads();
#pragma unroll
  for (int r = 0; r < 16; ++r) {
    int nn = tg * 16 + r;
    Wt[(size_t)(n0 + nn) * K + k0 + tx] = __float2bfloat16(tile[tx][nn]);
  }
}

// ---------------- GEMM: C[M][N] = A[M][K] * Bt[N][K]^T ----------------
template <bool OUT_BF16>
__global__ __launch_bounds__(256) void k_gemm_bt(const bf16* __restrict__ A,
                                                 const bf16* __restrict__ Bt,
                                                 void* __restrict__ Cout,
                                                 int M, int N, int K) {
  __shared__ bf16 As[128 * 32];
  __shared__ bf16 Bs[128 * 32];
  const int lane = threadIdx.x & 63;
  const int w = threadIdx.x >> 6;
  const int wr = w >> 1, wc = w & 1;
  const int li = lane & 15, g = lane >> 4;
  const int m0 = blockIdx.y * 128, n0 = blockIdx.x * 128;
  const int lrow = lane >> 2;     // 0..15
  const int lk = (lane & 3) * 8;  // 0,8,16,24

  f32x4 acc[4][4] = {};

  for (int k0 = 0; k0 < K; k0 += 32) {
#pragma unroll
    for (int it = 0; it < 2; ++it) {
      int c = w * 2 + it;
      const bf16* ga = A + (size_t)(m0 + c * 16 + lrow) * K + k0 + lk;
      gload_lds16(ga, &As[c * 512]);
      const bf16* gb = Bt + (size_t)(n0 + c * 16 + lrow) * K + k0 + lk;
      gload_lds16(gb, &Bs[c * 512]);
    }
    __syncthreads();

    bf16x8 af[4], bfr[4];
#pragma unroll
    for (int m = 0; m < 4; ++m)
      af[m] = *(const bf16x8*)&As[(wr * 64 + m * 16 + li) * 32 + g * 8];
#pragma unroll
    for (int n = 0; n < 4; ++n)
      bfr[n] = *(const bf16x8*)&Bs[(wc * 64 + n * 16 + li) * 32 + g * 8];
#pragma unroll
    for (int m = 0; m < 4; ++m)
#pragma unroll
      for (int n = 0; n < 4; ++n)
        acc[m][n] = __builtin_amdgcn_mfma_f32_16x16x32_bf16(af[m], bfr[n], acc[m][n], 0, 0, 0);
    __syncthreads();
  }

#pragma unroll
  for (int m = 0; m < 4; ++m)
#pragma unroll
    for (int n = 0; n < 4; ++n)
#pragma unroll
      for (int r = 0; r < 4; ++r) {
        int row = m0 + wr * 64 + m * 16 + g * 4 + r;
        int col = n0 + wc * 64 + n * 16 + li;
        float v = acc[m][n][r];
        if (OUT_BF16)
          ((bf16*)Cout)[(size_t)row * N + col] = __float2bfloat16(v);
        else
          ((float*)Cout)[(size_t)row * N + col] = v;
      }
}

// ---------------- RoPE (in place, bf16) ----------------
__global__ void k_rope(bf16* __restrict__ X, const float* __restrict__ cosT,
                       const float* __restrict__ sinT, int nheads, int total) {
  int p = blockIdx.x * blockDim.x + threadIdx.x;
  if (p >= total) return;
  int i = p & 63;
  int h = (p >> 6) % nheads;
  int bt = p / (64 * nheads);
  int t = bt & (T_ - 1);
  float c = cosT[t * 64 + i], s = sinT[t * 64 + i];
  size_t base = ((size_t)bt * nheads + h) * DH + 2 * i;
  float tr = __bfloat162float(X[base]);
  float ti = __bfloat162float(X[base + 1]);
  X[base] = __float2bfloat16(tr * c - ti * s);
  X[base + 1] = __float2bfloat16(tr * s + ti * c);
}

// ---------------- windowed flash attention ----------------
// grid: (T/16, B*NKV), block: 256 = 4 waves. Wave w handles head kvh*4+w,
// q rows t0..t0+15. All waves share the SAME (b,kvh) KV window -> K/V tiles
// staged once in LDS (coalesced, double-buffered, XOR-swizzled) and reused 4x.
__global__ __launch_bounds__(256) void k_attn(const bf16* __restrict__ Q,
                                              const bf16* __restrict__ Kb,
                                              const bf16* __restrict__ VT,
                                              bf16* __restrict__ Y) {
  __shared__ bf16 Ks[2][32 * 128];  // [key][dh], swizzled phys = o ^ ((row&7)<<4)
  __shared__ bf16 Vs[2][128 * 32];  // V^T tile [d][key], swizzled (bit-6 spill, bijective)
  __shared__ bf16 Plds[4][16 * 32];
  const int lane = threadIdx.x & 63;
  const int w = threadIdx.x >> 6;
  const int li = lane & 15, g = lane >> 4;
  const int t0 = blockIdx.x * 16;
  const int b = blockIdx.y / NKV, kvh = blockIdx.y % NKV;
  const int h = kvh * 4 + w;

  bf16x8 qf[4];
  const bf16* qbase = Q + ((size_t)(b * T_ + t0 + li) * NH + h) * DH;
#pragma unroll
  for (int dk = 0; dk < 4; ++dk) qf[dk] = *(const bf16x8*)(qbase + dk * 32 + g * 8);

  float mrow[4] = {-1e30f, -1e30f, -1e30f, -1e30f};
  float srow[4] = {0.f, 0.f, 0.f, 0.f};
  f32x4 acc[8] = {};

  const float scale = 0.08838834764831845f;  // 1/sqrt(128)

  int ks0 = t0 - (WIN - 1);
  if (ks0 < 0) ks0 = 0;
  ks0 &= ~31;
  const int nt = (t0 + 15 - ks0) / 32 + 1;

  const bf16* vtbase = VT + (size_t)(kvh * DH) * (B_ * T_) + b * T_;

  // stage one 32-key tile (K: 8KB, V^T: 8KB) into buf; 4 chunks per wave
  auto STAGE = [&](int buf, int kt) {
#pragma unroll
    for (int it = 0; it < 2; ++it) {
      int c = w * 2 + it;
      {  // K chunk: phys bytes c*1024 + lane*16
        int op = c * 1024 + lane * 16;
        int row = op >> 8;                    // key 0..31
        int ol = op ^ ((row & 7) << 4);       // logical byte
        int col = ol & 255;                   // byte in row
        const bf16* src = Kb + ((size_t)(b * T_ + kt + row) * NKV + kvh) * DH + col / 2;
        gload_lds16(src, (char*)&Ks[buf][0] + c * 1024);
      }
      {  // V chunk
        int op = c * 1024 + lane * 16;
        int row3 = ((op >> 6) & 7) ^ ((op >> 8) & 1);
        int ol = op ^ (row3 << 4);
        int d = ol >> 6;                      // 0..127
        int key = (ol & 63) >> 1;             // 0,8,16,24
        const bf16* src = vtbase + (size_t)d * (B_ * T_) + kt + key;
        gload_lds16(src, (char*)&Vs[buf][0] + c * 1024);
      }
    }
  };

  STAGE(0, ks0);
  __syncthreads();
  int cur = 0;

  for (int it = 0; it < nt; ++it) {
    const int kt = ks0 + it * 32;
    if (it + 1 < nt) STAGE(cur ^ 1, kt + 32);

    const char* ksb = (const char*)&Ks[cur][0];
    const char* vsb = (const char*)&Vs[cur][0];

    f32x4 s[2] = {};
#pragma unroll
    for (int n = 0; n < 2; ++n)
#pragma unroll
      for (int dk = 0; dk < 4; ++dk) {
        bf16x8 kf = *(const bf16x8*)(ksb + (n * 16 + li) * 256 +
                                     ((dk * 64 + g * 16) ^ ((li & 7) << 4)));
        s[n] = __builtin_amdgcn_mfma_f32_16x16x32_bf16(qf[dk], kf, s[n], 0, 0, 0);
      }

    float p[2][4], tmax[4];
#pragma unroll
    for (int r = 0; r < 4; ++r) {
      int t = t0 + g * 4 + r;
#pragma unroll
      for (int n = 0; n < 2; ++n) {
        int key = kt + n * 16 + li;
        bool valid = (key <= t) && (key >= t - (WIN - 1));
        p[n][r] = valid ? s[n][r] * scale : -1e30f;
      }
      tmax[r] = fmaxf(p[0][r], p[1][r]);
    }
#pragma unroll
    for (int mk = 1; mk < 16; mk <<= 1)
#pragma unroll
      for (int r = 0; r < 4; ++r) tmax[r] = fmaxf(tmax[r], __shfl_xor(tmax[r], mk));

    float alpha[4], rs[4];
#pragma unroll
    for (int r = 0; r < 4; ++r) {
      float nm = fmaxf(mrow[r], tmax[r]);
      alpha[r] = __expf(mrow[r] - nm);
      mrow[r] = nm;
#pragma unroll
      for (int n = 0; n < 2; ++n)
        p[n][r] = (p[n][r] <= -1e29f) ? 0.f : __expf(p[n][r] - nm);
      rs[r] = p[0][r] + p[1][r];
    }
#pragma unroll
    for (int mk = 1; mk < 16; mk <<= 1)
#pragma unroll
      for (int r = 0; r < 4; ++r) rs[r] += __shfl_xor(rs[r], mk);
#pragma unroll
    for (int r = 0; r < 4; ++r) srow[r] = srow[r] * alpha[r] + rs[r];
#pragma unroll
    for (int db = 0; db < 8; ++db)
#pragma unroll
      for (int r = 0; r < 4; ++r) acc[db][r] *= alpha[r];

    // P -> LDS (wave-private; intra-wave ordering via compiler lgkmcnt)
#pragma unroll
    for (int r = 0; r < 4; ++r)
#pragma unroll
      for (int n = 0; n < 2; ++n)
        Plds[w][(g * 4 + r) * 32 + n * 16 + li] = __float2bfloat16(p[n][r]);

    bf16x8 pf = *(const bf16x8*)&Plds[w][li * 32 + g * 8];
#pragma unroll
    for (int db = 0; db < 8; ++db) {
      bf16x8 vf = *(const bf16x8*)(vsb + (((db * 16 + li) * 64 + g * 16) ^ ((li & 7) << 4)));
      acc[db] = __builtin_amdgcn_mfma_f32_16x16x32_bf16(pf, vf, acc[db], 0, 0, 0);
    }

    __syncthreads();  // drains stage vmcnt + protects buffer swap
    cur ^= 1;
  }

  bf16* ybase = Y + ((size_t)(b * T_ + t0 + g * 4) * NH + h) * DH;
#pragma unroll
  for (int r = 0; r < 4; ++r) {
    float inv = 1.f / srow[r];
#pragma unroll
    for (int db = 0; db < 8; ++db)
      ybase[(size_t)r * NH * DH + db * 16 + li] = __float2bfloat16(acc[db][r] * inv);
  }
}

extern "C" void kernel_launch(void* const* d_in, const int* in_sizes, int n_in,
                              void* d_out, int out_size, void* d_ws, size_t ws_size,
                              hipStream_t stream) {
  const float* x = (const float*)d_in[0];
  const float* cosT = (const float*)d_in[1];
  const float* sinT = (const float*)d_in[2];
  const float* Wq = (const float*)d_in[3];
  const float* Wk = (const float*)d_in[4];
  const float* Wv = (const float*)d_in[5];
  const float* Wo = (const float*)d_in[6];
  float* out = (float*)d_out;

  char* ws = (char*)d_ws;
  bf16* xb = (bf16*)ws;   ws += (size_t)4096 * 2048 * 2;   // 16 MB (reused as yb)
  bf16* Wqt = (bf16*)ws;  ws += (size_t)2048 * 2048 * 2;   // 8 MB
  bf16* Wkt = (bf16*)ws;  ws += (size_t)512 * 2048 * 2;    // 2 MB
  bf16* Wvt = (bf16*)ws;  ws += (size_t)512 * 2048 * 2;    // 2 MB
  bf16* Wot = (bf16*)ws;  ws += (size_t)2048 * 2048 * 2;   // 8 MB
  bf16* qb = (bf16*)ws;   ws += (size_t)4096 * 2048 * 2;   // 16 MB
  bf16* kb = (bf16*)ws;   ws += (size_t)4096 * 512 * 2;    // 4 MB
  bf16* vt = (bf16*)ws;   ws += (size_t)512 * 4096 * 2;    // 4 MB  (V^T: [NKV*DH][B*T])
  bf16* yb = xb;  // xb dead after QKV GEMMs

  k_f32_to_bf16<<<(4096 * 2048 / 4 + 255) / 256, 256, 0, stream>>>(x, xb, 4096 * 2048);
  k_transpose_bf16<<<dim3(2048 / 64, 2048 / 64), 256, 0, stream>>>(Wq, Wqt, 2048, 2048);
  k_transpose_bf16<<<dim3(512 / 64, 2048 / 64), 256, 0, stream>>>(Wk, Wkt, 2048, 512);
  k_transpose_bf16<<<dim3(512 / 64, 2048 / 64), 256, 0, stream>>>(Wv, Wvt, 2048, 512);
  k_transpose_bf16<<<dim3(2048 / 64, 2048 / 64), 256, 0, stream>>>(Wo, Wot, 2048, 2048);

  k_gemm_bt<true><<<dim3(2048 / 128, 4096 / 128), 256, 0, stream>>>(xb, Wqt, qb, 4096, 2048, 2048);
  k_gemm_bt<true><<<dim3(512 / 128, 4096 / 128), 256, 0, stream>>>(xb, Wkt, kb, 4096, 512, 2048);
  // V^T = Wvt * xb^T  (same bt-GEMM with operands swapped): vt[n][m] over [512][4096]
  k_gemm_bt<true><<<dim3(4096 / 128, 512 / 128), 256, 0, stream>>>(Wvt, xb, vt, 512, 4096, 2048);

  k_rope<<<(B_ * T_ * NH * 64) / 256, 256, 0, stream>>>(qb, cosT, sinT, NH, B_ * T_ * NH * 64);
  k_rope<<<(B_ * T_ * NKV * 64) / 256, 256, 0, stream>>>(kb, cosT, sinT, NKV, B_ * T_ * NKV * 64);

  k_attn<<<dim3(T_ / 16, B_ * NKV), 256, 0, stream>>>(qb, kb, vt, yb);

  k_gemm_bt<false><<<dim3(2048 / 128, 4096 / 128), 256, 0, stream>>>(yb, Wot, out, 4096, 2048, 2048);
}

// Round 4
// 207.706 us; speedup vs baseline: 1.7922x; 1.5614x over previous
//
#include <hip/hip_runtime.h>
#include <hip/hip_bf16.h>
#include <cstdint>
#include <cstddef>

#define B_ 2
#define T_ 2048
#define NH 16
#define NKV 4
#define DH 128
#define DM 2048
#define WIN 512

typedef __attribute__((ext_vector_type(4))) float f32x4;
typedef __attribute__((ext_vector_type(8))) __bf16 bf16x8;

using bf16 = __hip_bfloat16;

__device__ inline void gload_lds16(const void* g, void* l) {
  __builtin_amdgcn_global_load_lds(
      (const __attribute__((address_space(1))) void*)g,
      (__attribute__((address_space(3))) void*)l, 16, 0, 0);
}

__device__ inline unsigned pack_bf2(float a, float b) {
  unsigned short ua = __builtin_bit_cast(unsigned short, __float2bfloat16(a));
  unsigned short ub = __builtin_bit_cast(unsigned short, __float2bfloat16(b));
  return (unsigned)ua | ((unsigned)ub << 16);
}

// ---------------- fp32 -> bf16 convert ----------------
__global__ void k_f32_to_bf16(const float* __restrict__ in, bf16* __restrict__ out, int n) {
  int i = (blockIdx.x * blockDim.x + threadIdx.x) * 4;
  if (i >= n) return;
  float4 v = *(const float4*)(in + i);
  ushort4 o;
  o.x = __builtin_bit_cast(unsigned short, __float2bfloat16(v.x));
  o.y = __builtin_bit_cast(unsigned short, __float2bfloat16(v.y));
  o.z = __builtin_bit_cast(unsigned short, __float2bfloat16(v.z));
  o.w = __builtin_bit_cast(unsigned short, __float2bfloat16(v.w));
  *(ushort4*)(out + i) = o;
}

// ---------------- W (K x N fp32) -> Wt (N x K bf16) ----------------
__global__ __launch_bounds__(256) void k_transpose_bf16(const float* __restrict__ W,
                                                        bf16* __restrict__ Wt, int K, int N) {
  __shared__ float tile[64][65];
  int n0 = blockIdx.x * 64, k0 = blockIdx.y * 64;
  int tx = threadIdx.x & 63, tg = threadIdx.x >> 6;
#pragma unroll
  for (int r = 0; r < 16; ++r) {
    int k = tg * 16 + r;
    tile[k][tx] = W[(size_t)(k0 + k) * N + n0 + tx];
  }
  __syncthreads();
#pragma unroll
  for (int r = 0; r < 16; ++r) {
    int nn = tg * 16 + r;
    Wt[(size_t)(n0 + nn) * K + k0 + tx] = __float2bfloat16(tile[tx][nn]);
  }
}

// ---------------- GEMM: C[M][N] = A[M][K] * Bt[N][K]^T ----------------
template <bool OUT_BF16>
__global__ __launch_bounds__(256) void k_gemm_bt(const bf16* __restrict__ A,
                                                 const bf16* __restrict__ Bt,
                                                 void* __restrict__ Cout,
                                                 int M, int N, int K) {
  __shared__ bf16 As[128 * 32];
  __shared__ bf16 Bs[128 * 32];
  const int lane = threadIdx.x & 63;
  const int w = threadIdx.x >> 6;
  const int wr = w >> 1, wc = w & 1;
  const int li = lane & 15, g = lane >> 4;
  const int m0 = blockIdx.y * 128, n0 = blockIdx.x * 128;
  const int lrow = lane >> 2;     // 0..15
  const int lk = (lane & 3) * 8;  // 0,8,16,24

  f32x4 acc[4][4] = {};

  for (int k0 = 0; k0 < K; k0 += 32) {
#pragma unroll
    for (int it = 0; it < 2; ++it) {
      int c = w * 2 + it;
      const bf16* ga = A + (size_t)(m0 + c * 16 + lrow) * K + k0 + lk;
      gload_lds16(ga, &As[c * 512]);
      const bf16* gb = Bt + (size_t)(n0 + c * 16 + lrow) * K + k0 + lk;
      gload_lds16(gb, &Bs[c * 512]);
    }
    __syncthreads();

    bf16x8 af[4], bfr[4];
#pragma unroll
    for (int m = 0; m < 4; ++m)
      af[m] = *(const bf16x8*)&As[(wr * 64 + m * 16 + li) * 32 + g * 8];
#pragma unroll
    for (int n = 0; n < 4; ++n)
      bfr[n] = *(const bf16x8*)&Bs[(wc * 64 + n * 16 + li) * 32 + g * 8];
#pragma unroll
    for (int m = 0; m < 4; ++m)
#pragma unroll
      for (int n = 0; n < 4; ++n)
        acc[m][n] = __builtin_amdgcn_mfma_f32_16x16x32_bf16(af[m], bfr[n], acc[m][n], 0, 0, 0);
    __syncthreads();
  }

#pragma unroll
  for (int m = 0; m < 4; ++m)
#pragma unroll
    for (int n = 0; n < 4; ++n)
#pragma unroll
      for (int r = 0; r < 4; ++r) {
        int row = m0 + wr * 64 + m * 16 + g * 4 + r;
        int col = n0 + wc * 64 + n * 16 + li;
        float v = acc[m][n][r];
        if (OUT_BF16)
          ((bf16*)Cout)[(size_t)row * N + col] = __float2bfloat16(v);
        else
          ((float*)Cout)[(size_t)row * N + col] = v;
      }
}

// ---------------- RoPE over fused qkv (in place); q heads also pre-scaled ----
// qkv row layout: [q 16*128 | k 4*128 | v 4*128] = 3072 cols. h20: 0-15 q, 16-19 k.
__global__ void k_rope_qkv(bf16* __restrict__ qkv, const float* __restrict__ cosT,
                           const float* __restrict__ sinT) {
  int p = blockIdx.x * blockDim.x + threadIdx.x;
  int i = p & 63;
  int h20 = (p >> 6) % 20;
  int bt = p / (64 * 20);
  int t = bt & (T_ - 1);
  float c = cosT[t * 64 + i], s = sinT[t * 64 + i];
  bool isq = h20 < 16;
  int col = isq ? h20 * DH : DM + (h20 - 16) * DH;
  float sc = isq ? 0.08838834764831845f : 1.0f;  // fold 1/sqrt(128) into Q
  size_t base = (size_t)bt * 3072 + col + 2 * i;
  float tr = __bfloat162float(qkv[base]);
  float ti = __bfloat162float(qkv[base + 1]);
  qkv[base] = __float2bfloat16((tr * c - ti * s) * sc);
  qkv[base + 1] = __float2bfloat16((tr * s + ti * c) * sc);
}

// ---------------- V slice of qkv -> V^T [NKV*DH][B*T] ----------------
__global__ __launch_bounds__(256) void k_vtrans(const bf16* __restrict__ qkv,
                                                bf16* __restrict__ vt) {
  __shared__ bf16 tile[64][72];
  int bt0 = blockIdx.x * 64, c0 = blockIdx.y * 64;
  int tx = threadIdx.x & 63, tg = threadIdx.x >> 6;
#pragma unroll
  for (int r = 0; r < 16; ++r) {
    int row = tg * 16 + r;
    tile[row][tx] = qkv[(size_t)(bt0 + row) * 3072 + 2560 + c0 + tx];
  }
  __syncthreads();
#pragma unroll
  for (int r = 0; r < 16; ++r) {
    int row2 = tg * 16 + r;
    vt[(size_t)(c0 + row2) * (B_ * T_) + bt0 + tx] = tile[tx][row2];
  }
}

// ---------------- windowed flash attention, swapped QK^T ----------------
// grid: (T/32 [reversed], B*NKV), block: 512 = 8 waves.
// wave w: head kvh*4 + (w>>1), q rows t0 + (w&1)*16 .. +15.
// All waves share K/V LDS staging (padded rows, double-buffered).
// mfma(K,Q): lane holds 8 scores of q-row (t0'+li) -> in-register softmax.
__global__ __launch_bounds__(512) void k_attn(const bf16* __restrict__ qkv,
                                              const bf16* __restrict__ vt,
                                              bf16* __restrict__ Y) {
  // K tile: 32 keys x 128 dh, rows padded 256->272B (17 x 16B chunks)
  // V^T tile: 128 d x 32 keys, rows padded 64->80B (5 x 16B chunks)
  __shared__ __align__(16) char Ks[2][9216];   // 544 data chunks + 32 junk
  __shared__ __align__(16) char Vs[2][10240];  // 640 chunks exact
  __shared__ __align__(16) char Pl[8][1280];   // per-wave P [16 q][40 pad keys]
  const int lane = threadIdx.x & 63;
  const int w = threadIdx.x >> 6;
  const int li = lane & 15, g = lane >> 4;
  const int t0 = ((int)gridDim.x - 1 - (int)blockIdx.x) * 32;  // long blocks first
  const int b = blockIdx.y / NKV, kvh = blockIdx.y % NKV;
  const int h = kvh * 4 + (w >> 1);
  const int qrow0 = t0 + (w & 1) * 16;
  const int t = qrow0 + li;  // this lane's q-row

  bf16x8 qf[4];
  const bf16* qbase = qkv + (size_t)(b * T_ + qrow0 + li) * 3072 + h * DH;
#pragma unroll
  for (int dk = 0; dk < 4; ++dk) qf[dk] = *(const bf16x8*)(qbase + dk * 32 + g * 8);

  float mrow = -1e4f;  // below any real max; exp(-1e30 - mrow) still 0
  float srow = 0.f;
  f32x4 acc[8] = {};

  int ks0 = t0 - (WIN - 1);
  if (ks0 < 0) ks0 = 0;
  ks0 &= ~31;
  const int nt = (t0 + 31 - ks0) / 32 + 1;

  const bf16* kgbase = qkv + (size_t)(b * T_) * 3072 + DM + kvh * DH;
  const bf16* vgbase = vt + (size_t)(kvh * DH) * (B_ * T_) + b * T_;

  auto STAGE = [&](int buf, int kt) {
    for (int c = w; c < 19; c += 8) {
      if (c < 9) {  // K: 544 data chunks of 16B
        int slot = c * 64 + lane;
        int row = slot / 17, cc = slot % 17;
        if (slot >= 544) { row = 0; cc = 0; }
        if (cc == 16) cc = 0;  // pad chunk: harmless dup of row start
        const bf16* src = kgbase + (size_t)(kt + row) * 3072 + cc * 8;
        gload_lds16(src, Ks[buf] + c * 1024);
      } else {  // V^T: 640 chunks
        int c2 = c - 9;
        int slot = c2 * 64 + lane;
        int row = slot / 5, cc = slot % 5;
        if (cc == 4) cc = 0;  // pad chunk
        const bf16* src = vgbase + (size_t)row * (B_ * T_) + kt + cc * 8;
        gload_lds16(src, Vs[buf] + c2 * 1024);
      }
    }
  };

  STAGE(0, ks0);
  __syncthreads();
  int cur = 0;

  for (int it = 0; it < nt; ++it) {
    const int kt = ks0 + it * 32;
    if (it + 1 < nt) STAGE(cur ^ 1, kt + 32);

    // QK^T swapped: A=K (rows=keys), B=Q (cols=q) -> lane holds S[key][q=li]
    f32x4 sc[2] = {};
#pragma unroll
    for (int n = 0; n < 2; ++n)
#pragma unroll
      for (int dk = 0; dk < 4; ++dk) {
        bf16x8 kf = *(const bf16x8*)(Ks[cur] + (n * 16 + li) * 272 + dk * 64 + g * 16);
        sc[n] = __builtin_amdgcn_mfma_f32_16x16x32_bf16(kf, qf[dk], sc[n], 0, 0, 0);
      }

    float p[2][4];
    float pmax = -1e30f;
#pragma unroll
    for (int n = 0; n < 2; ++n)
#pragma unroll
      for (int r = 0; r < 4; ++r) {
        int key = kt + n * 16 + g * 4 + r;
        bool valid = (key <= t) && (key > t - WIN);
        float pv = valid ? sc[n][r] : -1e30f;
        p[n][r] = pv;
        pmax = fmaxf(pmax, pv);
      }
    pmax = fmaxf(pmax, __shfl_xor(pmax, 16));
    pmax = fmaxf(pmax, __shfl_xor(pmax, 32));

    float nm = fmaxf(mrow, pmax);
    float alpha = __expf(mrow - nm);
    mrow = nm;
    float rs = 0.f;
#pragma unroll
    for (int n = 0; n < 2; ++n)
#pragma unroll
      for (int r = 0; r < 4; ++r) {
        p[n][r] = __expf(p[n][r] - nm);  // masked: exp(-huge) == 0
        rs += p[n][r];
      }
    rs += __shfl_xor(rs, 16);
    rs += __shfl_xor(rs, 32);
    srow = srow * alpha + rs;

    // P -> LDS: Pl[w][q=li][key], packed pairs (keys n*16+g*4 + {0,1},{2,3})
#pragma unroll
    for (int n = 0; n < 2; ++n) {
      *(unsigned*)(Pl[w] + li * 80 + n * 32 + g * 8) = pack_bf2(p[n][0], p[n][1]);
      *(unsigned*)(Pl[w] + li * 80 + n * 32 + g * 8 + 4) = pack_bf2(p[n][2], p[n][3]);
    }

    // rescale acc by alpha of row (qrow0 + g*4 + r)
    float af_[4];
#pragma unroll
    for (int r = 0; r < 4; ++r) af_[r] = __shfl(alpha, (g << 2) + r);
#pragma unroll
    for (int db = 0; db < 8; ++db)
#pragma unroll
      for (int r = 0; r < 4; ++r) acc[db][r] *= af_[r];

    // PV: A=P (rows=q), B=V^T (cols=d)
    bf16x8 pf = *(const bf16x8*)(Pl[w] + li * 80 + g * 16);
#pragma unroll
    for (int db = 0; db < 8; ++db) {
      bf16x8 vf = *(const bf16x8*)(Vs[cur] + (db * 16 + li) * 80 + g * 16);
      acc[db] = __builtin_amdgcn_mfma_f32_16x16x32_bf16(pf, vf, acc[db], 0, 0, 0);
    }

    __syncthreads();  // drains staging vmcnt + protects buffer reuse
    cur ^= 1;
  }

  float inv[4];
#pragma unroll
  for (int r = 0; r < 4; ++r) inv[r] = 1.f / __shfl(srow, (g << 2) + r);
  bf16* ybase = Y + (size_t)(b * T_ + qrow0 + (g << 2)) * DM + h * DH;
#pragma unroll
  for (int r = 0; r < 4; ++r)
#pragma unroll
    for (int db = 0; db < 8; ++db)
      ybase[(size_t)r * DM + db * 16 + li] = __float2bfloat16(acc[db][r] * inv[r]);
}

extern "C" void kernel_launch(void* const* d_in, const int* in_sizes, int n_in,
                              void* d_out, int out_size, void* d_ws, size_t ws_size,
                              hipStream_t stream) {
  const float* x = (const float*)d_in[0];
  const float* cosT = (const float*)d_in[1];
  const float* sinT = (const float*)d_in[2];
  const float* Wq = (const float*)d_in[3];
  const float* Wk = (const float*)d_in[4];
  const float* Wv = (const float*)d_in[5];
  const float* Wo = (const float*)d_in[6];
  float* out = (float*)d_out;

  char* ws = (char*)d_ws;
  bf16* xb = (bf16*)ws;     ws += (size_t)4096 * 2048 * 2;  // 16.8 MB (reused as yb)
  bf16* Wqkvt = (bf16*)ws;  ws += (size_t)3072 * 2048 * 2;  // 12.6 MB (reused as vt)
  bf16* Wot = (bf16*)ws;    ws += (size_t)2048 * 2048 * 2;  // 8.4 MB
  bf16* qkv = (bf16*)ws;    ws += (size_t)4096 * 3072 * 2;  // 25.2 MB
  bf16* yb = xb;                      // xb dead after QKV GEMM
  bf16* vt = Wqkvt;                   // Wqkvt dead after QKV GEMM

  k_f32_to_bf16<<<(4096 * 2048 / 4 + 255) / 256, 256, 0, stream>>>(x, xb, 4096 * 2048);
  // fused weight: rows [0,2048)=Wq^T, [2048,2560)=Wk^T, [2560,3072)=Wv^T
  k_transpose_bf16<<<dim3(2048 / 64, 2048 / 64), 256, 0, stream>>>(Wq, Wqkvt, 2048, 2048);
  k_transpose_bf16<<<dim3(512 / 64, 2048 / 64), 256, 0, stream>>>(Wk, Wqkvt + (size_t)2048 * 2048, 2048, 512);
  k_transpose_bf16<<<dim3(512 / 64, 2048 / 64), 256, 0, stream>>>(Wv, Wqkvt + (size_t)2560 * 2048, 2048, 512);
  k_transpose_bf16<<<dim3(2048 / 64, 2048 / 64), 256, 0, stream>>>(Wo, Wot, 2048, 2048);

  k_gemm_bt<true><<<dim3(3072 / 128, 4096 / 128), 256, 0, stream>>>(xb, Wqkvt, qkv, 4096, 3072, 2048);

  k_rope_qkv<<<(4096 * 20 * 64) / 256, 256, 0, stream>>>(qkv, cosT, sinT);
  k_vtrans<<<dim3(4096 / 64, 512 / 64), 256, 0, stream>>>(qkv, vt);

  k_attn<<<dim3(T_ / 32, B_ * NKV), 512, 0, stream>>>(qkv, vt, yb);

  k_gemm_bt<false><<<dim3(2048 / 128, 4096 / 128), 256, 0, stream>>>(yb, Wot, out, 4096, 2048, 2048);
}

// Round 5
// 183.607 us; speedup vs baseline: 2.0274x; 1.1313x over previous
//
#include <hip/hip_runtime.h>
#include <hip/hip_bf16.h>
#include <cstdint>
#include <cstddef>

#define B_ 2
#define T_ 2048
#define NH 16
#define NKV 4
#define DH 128
#define DM 2048
#define WIN 512

typedef __attribute__((ext_vector_type(4))) float f32x4;
typedef __attribute__((ext_vector_type(8))) __bf16 bf16x8;

using bf16 = __hip_bfloat16;

__device__ inline void gload_lds16(const void* g, void* l) {
  __builtin_amdgcn_global_load_lds(
      (const __attribute__((address_space(1))) void*)g,
      (__attribute__((address_space(3))) void*)l, 16, 0, 0);
}

__device__ inline unsigned pack_bf2(float a, float b) {
  unsigned short ua = __builtin_bit_cast(unsigned short, __float2bfloat16(a));
  unsigned short ub = __builtin_bit_cast(unsigned short, __float2bfloat16(b));
  return (unsigned)ua | ((unsigned)ub << 16);
}

#define FBAR()                           \
  do {                                   \
    asm volatile("" ::: "memory");       \
    __builtin_amdgcn_s_barrier();        \
    asm volatile("" ::: "memory");       \
  } while (0)

// ---------------- fp32 -> bf16 convert ----------------
__global__ void k_f32_to_bf16(const float* __restrict__ in, bf16* __restrict__ out, int n) {
  int i = (blockIdx.x * blockDim.x + threadIdx.x) * 4;
  if (i >= n) return;
  float4 v = *(const float4*)(in + i);
  ushort4 o;
  o.x = __builtin_bit_cast(unsigned short, __float2bfloat16(v.x));
  o.y = __builtin_bit_cast(unsigned short, __float2bfloat16(v.y));
  o.z = __builtin_bit_cast(unsigned short, __float2bfloat16(v.z));
  o.w = __builtin_bit_cast(unsigned short, __float2bfloat16(v.w));
  *(ushort4*)(out + i) = o;
}

// ---------------- W (K x N fp32) -> Wt (N x K bf16) ----------------
__global__ __launch_bounds__(256) void k_transpose_bf16(const float* __restrict__ W,
                                                        bf16* __restrict__ Wt, int K, int N) {
  __shared__ float tile[64][65];
  int n0 = blockIdx.x * 64, k0 = blockIdx.y * 64;
  int tx = threadIdx.x & 63, tg = threadIdx.x >> 6;
#pragma unroll
  for (int r = 0; r < 16; ++r) {
    int k = tg * 16 + r;
    tile[k][tx] = W[(size_t)(k0 + k) * N + n0 + tx];
  }
  __syncthreads();
#pragma unroll
  for (int r = 0; r < 16; ++r) {
    int nn = tg * 16 + r;
    Wt[(size_t)(n0 + nn) * K + k0 + tx] = __float2bfloat16(tile[tx][nn]);
  }
}

// ======== 256-row 8-phase MFMA GEMM: C[M][N] = A[M][K] * Bt[N][K]^T ========
// BM=256, BK=64, 8 waves (2M x 4N), double-buffered LDS, XOR-swizzled rows,
// counted vmcnt (phases 4/8 only), raw barriers, setprio around MFMA.
template <int BN, bool OUT_BF16>
__global__ __launch_bounds__(512, 2) void k_gemm8(const bf16* __restrict__ A,
                                                  const bf16* __restrict__ Bt,
                                                  void* __restrict__ Cout,
                                                  int M, int N, int K) {
  constexpr int NR = BN / 64;    // n-frags per wave (4 or 2)
  constexpr int NHF = NR / 2;    // n-frags per half-phase (2 or 1)
  constexpr int BISS = BN / 128; // B stage-issues per half (2 or 1)
  __shared__ __align__(16) char As_[2][32768];
  __shared__ __align__(16) char Bs_[2][BN * 128];

  const int tid = threadIdx.x;
  const int w = tid >> 6, lane = tid & 63;
  const int li = lane & 15, g = lane >> 4;
  const int wm = w >> 2, wn = w & 3;

  // XCD-aware bijective swizzle (all launches have nwg % 8 == 0)
  const int nwg = gridDim.x * gridDim.y;
  int bid = blockIdx.y * gridDim.x + blockIdx.x;
  bid = (bid & 7) * (nwg >> 3) + (bid >> 3);
  const int m0 = (bid / gridDim.x) * 256;
  const int n0 = (bid % gridDim.x) * BN;

  const int ntiles = K >> 6;
  const int NT2 = ntiles >> 1;

  // ---- staging (linear LDS dest, inverse-swizzled global source) ----
  // A halves: A0 = rows {0-63,128-191} (per-wave M-half0), A1 = rest; 2 issues each.
  auto sA = [&](int buf, int tile, int half, int issue) {
    if (tile >= ntiles) return;
    const int R0 = half * 64 + issue * 128;
    const int rr = R0 + w * 8 + (lane >> 3);
    const int sl = lane & 7;
    const bf16* src = A + (size_t)(m0 + rr) * K + tile * 64 + ((sl ^ (rr & 7)) * 8);
    gload_lds16(src, As_[buf] + (R0 + w * 8) * 128);
  };
  auto sB = [&](int buf, int tile, int half, int issue) {
    if (tile >= ntiles) return;
    const int bb = issue * 8 + w;
    const int block = (BN == 256) ? ((bb >> 2) * 8 + (bb & 3) + half * 4)
                                  : ((bb >> 1) * 4 + (bb & 1) + half * 2);
    const int rr = block * 8 + (lane >> 3);
    const int sl = lane & 7;
    const bf16* src = Bt + (size_t)(n0 + rr) * K + tile * 64 + ((sl ^ (rr & 7)) * 8);
    gload_lds16(src, Bs_[buf] + block * 1024);
  };

  const int swz0 = (g ^ (li & 7)) * 16;
  const int swz1 = ((4 + g) ^ (li & 7)) * 16;
  bf16x8 af[8], b0v[NHF * 2], b1v[NHF * 2];
  f32x4 acc[8][NR] = {};

  auto readA = [&](int buf, int mh) {
#pragma unroll
    for (int m = 0; m < 4; ++m) {
      const char* p = As_[buf] + (wm * 128 + mh * 64 + m * 16 + li) * 128;
      af[m * 2 + 0] = *(const bf16x8*)(p + swz0);
      af[m * 2 + 1] = *(const bf16x8*)(p + swz1);
    }
  };
  auto readB = [&](int buf, int nh, bf16x8* bv) {
#pragma unroll
    for (int n = 0; n < NHF; ++n) {
      const char* p = Bs_[buf] + (wn * (NR * 16) + nh * (NHF * 16) + n * 16 + li) * 128;
      bv[n * 2 + 0] = *(const bf16x8*)(p + swz0);
      bv[n * 2 + 1] = *(const bf16x8*)(p + swz1);
    }
  };
  auto MMA = [&](int mh, int nh, const bf16x8* bv) {
    __builtin_amdgcn_s_setprio(1);
#pragma unroll
    for (int m = 0; m < 4; ++m)
#pragma unroll
      for (int n = 0; n < NHF; ++n)
#pragma unroll
        for (int kk = 0; kk < 2; ++kk)
          acc[mh * 4 + m][nh * NHF + n] = __builtin_amdgcn_mfma_f32_16x16x32_bf16(
              af[m * 2 + kk], bv[n * 2 + kk], acc[mh * 4 + m][nh * NHF + n], 0, 0, 0);
    __builtin_amdgcn_s_setprio(0);
  };
  auto VMW = [&](bool last) {
    if (last) {
      asm volatile("s_waitcnt vmcnt(0)" ::: "memory");
    } else {
      if constexpr (BN == 256)
        asm volatile("s_waitcnt vmcnt(4)" ::: "memory");
      else
        asm volatile("s_waitcnt vmcnt(3)" ::: "memory");
    }
    __builtin_amdgcn_sched_barrier(0);
  };

  // ---- prologue: tile0 full + tile1 A0/B0; wait tile0 ----
  sA(0, 0, 0, 0); sA(0, 0, 0, 1); sA(0, 0, 1, 0); sA(0, 0, 1, 1);
  sB(0, 0, 0, 0); if constexpr (BISS == 2) sB(0, 0, 0, 1);
  sB(0, 0, 1, 0); if constexpr (BISS == 2) sB(0, 0, 1, 1);
  sA(1, 1, 0, 0); sA(1, 1, 0, 1);
  sB(1, 1, 0, 0); if constexpr (BISS == 2) sB(1, 1, 0, 1);
  if constexpr (BN == 256)
    asm volatile("s_waitcnt vmcnt(4)" ::: "memory");
  else
    asm volatile("s_waitcnt vmcnt(3)" ::: "memory");
  __builtin_amdgcn_sched_barrier(0);
  FBAR();

  for (int itr = 0; itr < NT2; ++itr) {
    const int t = itr * 2;
    const bool last = (itr == NT2 - 1);
    // ph1: tile t (buf0) quad M0N0; stage (t+1).A1 -> buf1
    readA(0, 0); readB(0, 0, b0v);
    sA(1, t + 1, 1, 0); sA(1, t + 1, 1, 1);
    FBAR(); MMA(0, 0, b0v); FBAR();
    // ph2: M0N1; stage (t+1).B1
    readB(0, 1, b1v);
    sB(1, t + 1, 1, 0); if constexpr (BISS == 2) sB(1, t + 1, 1, 1);
    FBAR(); MMA(0, 1, b1v); FBAR();
    // ph3: M1N0; stage (t+2).A0 -> buf0 (region done after ph2)
    readA(0, 1);
    sA(0, t + 2, 0, 0); sA(0, t + 2, 0, 1);
    FBAR(); MMA(1, 0, b0v); FBAR();
    // ph4: M1N1; stage (t+2).B0; counted vmcnt (ensures tile t+1 landed)
    sB(0, t + 2, 0, 0); if constexpr (BISS == 2) sB(0, t + 2, 0, 1);
    VMW(last);
    FBAR(); MMA(1, 1, b1v); FBAR();
    // ph5: tile t+1 (buf1) M0N0; stage (t+2).A1
    readA(1, 0); readB(1, 0, b0v);
    sA(0, t + 2, 1, 0); sA(0, t + 2, 1, 1);
    FBAR(); MMA(0, 0, b0v); FBAR();
    // ph6: M0N1; stage (t+2).B1
    readB(1, 1, b1v);
    sB(0, t + 2, 1, 0); if constexpr (BISS == 2) sB(0, t + 2, 1, 1);
    FBAR(); MMA(0, 1, b1v); FBAR();
    // ph7: M1N0; stage (t+3).A0 -> buf1
    readA(1, 1);
    sA(1, t + 3, 0, 0); sA(1, t + 3, 0, 1);
    FBAR(); MMA(1, 0, b0v); FBAR();
    // ph8: M1N1; stage (t+3).B0; counted vmcnt (ensures tile t+2 landed)
    sB(1, t + 3, 0, 0); if constexpr (BISS == 2) sB(1, t + 3, 0, 1);
    VMW(last);
    FBAR(); MMA(1, 1, b1v); FBAR();
  }

#pragma unroll
  for (int mf = 0; mf < 8; ++mf)
#pragma unroll
    for (int nf = 0; nf < NR; ++nf)
#pragma unroll
      for (int r = 0; r < 4; ++r) {
        int row = m0 + wm * 128 + mf * 16 + g * 4 + r;
        int col = n0 + wn * (NR * 16) + nf * 16 + li;
        float v = acc[mf][nf][r];
        if constexpr (OUT_BF16)
          ((bf16*)Cout)[(size_t)row * N + col] = __float2bfloat16(v);
        else
          ((float*)Cout)[(size_t)row * N + col] = v;
      }
}

// ---------------- RoPE over fused qkv (in place); q heads also pre-scaled ----
__global__ void k_rope_qkv(bf16* __restrict__ qkv, const float* __restrict__ cosT,
                           const float* __restrict__ sinT) {
  int p = blockIdx.x * blockDim.x + threadIdx.x;
  int i = p & 63;
  int h20 = (p >> 6) % 20;
  int bt = p / (64 * 20);
  int t = bt & (T_ - 1);
  float c = cosT[t * 64 + i], s = sinT[t * 64 + i];
  bool isq = h20 < 16;
  int col = isq ? h20 * DH : DM + (h20 - 16) * DH;
  float sc = isq ? 0.08838834764831845f : 1.0f;  // fold 1/sqrt(128) into Q
  size_t base = (size_t)bt * 3072 + col + 2 * i;
  float tr = __bfloat162float(qkv[base]);
  float ti = __bfloat162float(qkv[base + 1]);
  qkv[base] = __float2bfloat16((tr * c - ti * s) * sc);
  qkv[base + 1] = __float2bfloat16((tr * s + ti * c) * sc);
}

// ---------------- V slice of qkv -> V^T [NKV*DH][B*T] ----------------
__global__ __launch_bounds__(256) void k_vtrans(const bf16* __restrict__ qkv,
                                                bf16* __restrict__ vt) {
  __shared__ bf16 tile[64][72];
  int bt0 = blockIdx.x * 64, c0 = blockIdx.y * 64;
  int tx = threadIdx.x & 63, tg = threadIdx.x >> 6;
#pragma unroll
  for (int r = 0; r < 16; ++r) {
    int row = tg * 16 + r;
    tile[row][tx] = qkv[(size_t)(bt0 + row) * 3072 + 2560 + c0 + tx];
  }
  __syncthreads();
#pragma unroll
  for (int r = 0; r < 16; ++r) {
    int row2 = tg * 16 + r;
    vt[(size_t)(c0 + row2) * (B_ * T_) + bt0 + tx] = tile[tx][row2];
  }
}

// ---------------- windowed flash attention, swapped QK^T ----------------
__global__ __launch_bounds__(512) void k_attn(const bf16* __restrict__ qkv,
                                              const bf16* __restrict__ vt,
                                              bf16* __restrict__ Y) {
  __shared__ __align__(16) char Ks[2][9216];
  __shared__ __align__(16) char Vs[2][10240];
  __shared__ __align__(16) char Pl[8][1280];
  const int lane = threadIdx.x & 63;
  const int w = threadIdx.x >> 6;
  const int li = lane & 15, g = lane >> 4;
  const int t0 = ((int)gridDim.x - 1 - (int)blockIdx.x) * 32;
  const int b = blockIdx.y / NKV, kvh = blockIdx.y % NKV;
  const int h = kvh * 4 + (w >> 1);
  const int qrow0 = t0 + (w & 1) * 16;
  const int t = qrow0 + li;

  bf16x8 qf[4];
  const bf16* qbase = qkv + (size_t)(b * T_ + qrow0 + li) * 3072 + h * DH;
#pragma unroll
  for (int dk = 0; dk < 4; ++dk) qf[dk] = *(const bf16x8*)(qbase + dk * 32 + g * 8);

  float mrow = -1e4f;
  float srow = 0.f;
  f32x4 acc[8] = {};

  int ks0 = t0 - (WIN - 1);
  if (ks0 < 0) ks0 = 0;
  ks0 &= ~31;
  const int nt = (t0 + 31 - ks0) / 32 + 1;

  const bf16* kgbase = qkv + (size_t)(b * T_) * 3072 + DM + kvh * DH;
  const bf16* vgbase = vt + (size_t)(kvh * DH) * (B_ * T_) + b * T_;

  auto STAGE = [&](int buf, int kt) {
    for (int c = w; c < 19; c += 8) {
      if (c < 9) {
        int slot = c * 64 + lane;
        int row = slot / 17, cc = slot % 17;
        if (slot >= 544) { row = 0; cc = 0; }
        if (cc == 16) cc = 0;
        const bf16* src = kgbase + (size_t)(kt + row) * 3072 + cc * 8;
        gload_lds16(src, Ks[buf] + c * 1024);
      } else {
        int c2 = c - 9;
        int slot = c2 * 64 + lane;
        int row = slot / 5, cc = slot % 5;
        if (cc == 4) cc = 0;
        const bf16* src = vgbase + (size_t)row * (B_ * T_) + kt + cc * 8;
        gload_lds16(src, Vs[buf] + c2 * 1024);
      }
    }
  };

  STAGE(0, ks0);
  __syncthreads();
  int cur = 0;

  for (int it = 0; it < nt; ++it) {
    const int kt = ks0 + it * 32;
    if (it + 1 < nt) STAGE(cur ^ 1, kt + 32);

    f32x4 sc[2] = {};
#pragma unroll
    for (int n = 0; n < 2; ++n)
#pragma unroll
      for (int dk = 0; dk < 4; ++dk) {
        bf16x8 kf = *(const bf16x8*)(Ks[cur] + (n * 16 + li) * 272 + dk * 64 + g * 16);
        sc[n] = __builtin_amdgcn_mfma_f32_16x16x32_bf16(kf, qf[dk], sc[n], 0, 0, 0);
      }

    float p[2][4];
    float pmax = -1e30f;
#pragma unroll
    for (int n = 0; n < 2; ++n)
#pragma unroll
      for (int r = 0; r < 4; ++r) {
        int key = kt + n * 16 + g * 4 + r;
        bool valid = (key <= t) && (key > t - WIN);
        float pv = valid ? sc[n][r] : -1e30f;
        p[n][r] = pv;
        pmax = fmaxf(pmax, pv);
      }
    pmax = fmaxf(pmax, __shfl_xor(pmax, 16));
    pmax = fmaxf(pmax, __shfl_xor(pmax, 32));

    float nm = fmaxf(mrow, pmax);
    float alpha = __expf(mrow - nm);
    mrow = nm;
    float rs = 0.f;
#pragma unroll
    for (int n = 0; n < 2; ++n)
#pragma unroll
      for (int r = 0; r < 4; ++r) {
        p[n][r] = __expf(p[n][r] - nm);
        rs += p[n][r];
      }
    rs += __shfl_xor(rs, 16);
    rs += __shfl_xor(rs, 32);
    srow = srow * alpha + rs;

#pragma unroll
    for (int n = 0; n < 2; ++n) {
      *(unsigned*)(Pl[w] + li * 80 + n * 32 + g * 8) = pack_bf2(p[n][0], p[n][1]);
      *(unsigned*)(Pl[w] + li * 80 + n * 32 + g * 8 + 4) = pack_bf2(p[n][2], p[n][3]);
    }

    float af_[4];
#pragma unroll
    for (int r = 0; r < 4; ++r) af_[r] = __shfl(alpha, (g << 2) + r);
#pragma unroll
    for (int db = 0; db < 8; ++db)
#pragma unroll
      for (int r = 0; r < 4; ++r) acc[db][r] *= af_[r];

    bf16x8 pf = *(const bf16x8*)(Pl[w] + li * 80 + g * 16);
#pragma unroll
    for (int db = 0; db < 8; ++db) {
      bf16x8 vf = *(const bf16x8*)(Vs[cur] + (db * 16 + li) * 80 + g * 16);
      acc[db] = __builtin_amdgcn_mfma_f32_16x16x32_bf16(pf, vf, acc[db], 0, 0, 0);
    }

    __syncthreads();
    cur ^= 1;
  }

  float inv[4];
#pragma unroll
  for (int r = 0; r < 4; ++r) inv[r] = 1.f / __shfl(srow, (g << 2) + r);
  bf16* ybase = Y + (size_t)(b * T_ + qrow0 + (g << 2)) * DM + h * DH;
#pragma unroll
  for (int r = 0; r < 4; ++r)
#pragma unroll
    for (int db = 0; db < 8; ++db)
      ybase[(size_t)r * DM + db * 16 + li] = __float2bfloat16(acc[db][r] * inv[r]);
}

extern "C" void kernel_launch(void* const* d_in, const int* in_sizes, int n_in,
                              void* d_out, int out_size, void* d_ws, size_t ws_size,
                              hipStream_t stream) {
  const float* x = (const float*)d_in[0];
  const float* cosT = (const float*)d_in[1];
  const float* sinT = (const float*)d_in[2];
  const float* Wq = (const float*)d_in[3];
  const float* Wk = (const float*)d_in[4];
  const float* Wv = (const float*)d_in[5];
  const float* Wo = (const float*)d_in[6];
  float* out = (float*)d_out;

  char* ws = (char*)d_ws;
  bf16* xb = (bf16*)ws;     ws += (size_t)4096 * 2048 * 2;
  bf16* Wqkvt = (bf16*)ws;  ws += (size_t)3072 * 2048 * 2;
  bf16* Wot = (bf16*)ws;    ws += (size_t)2048 * 2048 * 2;
  bf16* qkv = (bf16*)ws;    ws += (size_t)4096 * 3072 * 2;
  bf16* yb = xb;
  bf16* vt = Wqkvt;

  k_f32_to_bf16<<<(4096 * 2048 / 4 + 255) / 256, 256, 0, stream>>>(x, xb, 4096 * 2048);
  k_transpose_bf16<<<dim3(2048 / 64, 2048 / 64), 256, 0, stream>>>(Wq, Wqkvt, 2048, 2048);
  k_transpose_bf16<<<dim3(512 / 64, 2048 / 64), 256, 0, stream>>>(Wk, Wqkvt + (size_t)2048 * 2048, 2048, 512);
  k_transpose_bf16<<<dim3(512 / 64, 2048 / 64), 256, 0, stream>>>(Wv, Wqkvt + (size_t)2560 * 2048, 2048, 512);
  k_transpose_bf16<<<dim3(2048 / 64, 2048 / 64), 256, 0, stream>>>(Wo, Wot, 2048, 2048);

  k_gemm8<256, true><<<dim3(3072 / 256, 4096 / 256), 512, 0, stream>>>(xb, Wqkvt, qkv, 4096, 3072, 2048);

  k_rope_qkv<<<(4096 * 20 * 64) / 256, 256, 0, stream>>>(qkv, cosT, sinT);
  k_vtrans<<<dim3(4096 / 64, 512 / 64), 256, 0, stream>>>(qkv, vt);

  k_attn<<<dim3(T_ / 32, B_ * NKV), 512, 0, stream>>>(qkv, vt, yb);

  k_gemm8<128, false><<<dim3(2048 / 128, 4096 / 256), 512, 0, stream>>>(yb, Wot, out, 4096, 2048, 2048);
}

// Round 6
// 171.750 us; speedup vs baseline: 2.1673x; 1.0690x over previous
//
#include <hip/hip_runtime.h>
#include <hip/hip_bf16.h>
#include <cstdint>
#include <cstddef>

#define B_ 2
#define T_ 2048
#define NH 16
#define NKV 4
#define DH 128
#define DM 2048
#define WIN 512

typedef __attribute__((ext_vector_type(4))) float f32x4;
typedef __attribute__((ext_vector_type(8))) __bf16 bf16x8;

using bf16 = __hip_bfloat16;

__device__ inline void gload_lds16(const void* g, void* l) {
  __builtin_amdgcn_global_load_lds(
      (const __attribute__((address_space(1))) void*)g,
      (__attribute__((address_space(3))) void*)l, 16, 0, 0);
}

__device__ inline unsigned pack_bf2(float a, float b) {
  unsigned short ua = __builtin_bit_cast(unsigned short, __float2bfloat16(a));
  unsigned short ub = __builtin_bit_cast(unsigned short, __float2bfloat16(b));
  return (unsigned)ua | ((unsigned)ub << 16);
}

#define FBAR()                           \
  do {                                   \
    asm volatile("" ::: "memory");       \
    __builtin_amdgcn_s_barrier();        \
    asm volatile("" ::: "memory");       \
  } while (0)

// ---------------- prep: x fp32->bf16 + all weight transposes ----------------
// blocks [0,1024): Wq -> Wqkvt[0..2048)          (32 n-tiles x 32 k-tiles)
// [1024,1280): Wk -> Wqkvt[2048..2560)           (8 x 32)
// [1280,1536): Wv -> Wqkvt[2560..3072)           (8 x 32)
// [1536,2560): Wo -> Wot                          (32 x 32)
// [2560,4608): x fp32 -> xb bf16 (4096 elems / block)
__global__ __launch_bounds__(256) void k_prep(const float* __restrict__ x,
                                              const float* __restrict__ Wq,
                                              const float* __restrict__ Wk,
                                              const float* __restrict__ Wv,
                                              const float* __restrict__ Wo,
                                              bf16* __restrict__ xb,
                                              bf16* __restrict__ Wqkvt,
                                              bf16* __restrict__ Wot) {
  int id = blockIdx.x;
  int tid = threadIdx.x;
  if (id >= 2560) {  // convert
    size_t base = (size_t)(id - 2560) * 4096 + tid * 16;
#pragma unroll
    for (int j = 0; j < 4; ++j) {
      float4 v = *(const float4*)(x + base + j * 4);
      ushort4 o;
      o.x = __builtin_bit_cast(unsigned short, __float2bfloat16(v.x));
      o.y = __builtin_bit_cast(unsigned short, __float2bfloat16(v.y));
      o.z = __builtin_bit_cast(unsigned short, __float2bfloat16(v.z));
      o.w = __builtin_bit_cast(unsigned short, __float2bfloat16(v.w));
      *(ushort4*)(xb + base + j * 4) = o;
    }
    return;
  }
  const float* W;
  bf16* Wt;
  int N, bx, by;
  if (id < 1024) { W = Wq; Wt = Wqkvt; N = 2048; bx = id & 31; by = id >> 5; }
  else if (id < 1280) { id -= 1024; W = Wk; Wt = Wqkvt + (size_t)2048 * 2048; N = 512; bx = id & 7; by = id >> 3; }
  else if (id < 1536) { id -= 1280; W = Wv; Wt = Wqkvt + (size_t)2560 * 2048; N = 512; bx = id & 7; by = id >> 3; }
  else { id -= 1536; W = Wo; Wt = Wot; N = 2048; bx = id & 31; by = id >> 5; }

  __shared__ float tile[64][65];
  int n0 = bx * 64, k0 = by * 64;
  int tx = tid & 63, tg = tid >> 6;
#pragma unroll
  for (int r = 0; r < 16; ++r) {
    int k = tg * 16 + r;
    tile[k][tx] = W[(size_t)(k0 + k) * N + n0 + tx];
  }
  __syncthreads();
#pragma unroll
  for (int r = 0; r < 16; ++r) {
    int nn = tg * 16 + r;
    Wt[(size_t)(n0 + nn) * 2048 + k0 + tx] = __float2bfloat16(tile[tx][nn]);
  }
}

// ======== 256-row 8-phase MFMA GEMM: C[M][N] = A[M][K] * Bt[N][K]^T ========
// BM=256, BK=64, 8 waves (2M x 4N), double-buffered LDS, XOR-swizzled rows,
// counted vmcnt (phases 4/8 only), raw barriers, setprio around MFMA.
// N-halves may be asymmetric: NH0/NH1 frags per wave (BN=192 -> 2+1).
template <int BN, bool OUT_BF16>
__global__ __launch_bounds__(512, 2) void k_gemm8(const bf16* __restrict__ A,
                                                  const bf16* __restrict__ Bt,
                                                  void* __restrict__ Cout,
                                                  int M, int N, int K) {
  constexpr int NR = BN / 64;          // n-frags per wave
  constexpr int NH0 = (NR + 1) / 2;    // frags in N-half0
  constexpr int NH1 = NR - NH0;        // frags in N-half1
  constexpr int VMN = 2 + NH0;         // counted vmcnt
  __shared__ __align__(16) char As_[2][32768];
  __shared__ __align__(16) char Bs_[2][BN * 128];

  const int tid = threadIdx.x;
  const int w = tid >> 6, lane = tid & 63;
  const int li = lane & 15, g = lane >> 4;
  const int wm = w >> 2, wn = w & 3;

  const int nwg = gridDim.x * gridDim.y;
  int bid = blockIdx.y * gridDim.x + blockIdx.x;
  bid = (bid & 7) * (nwg >> 3) + (bid >> 3);
  const int m0 = (bid / gridDim.x) * 256;
  const int n0 = (bid % gridDim.x) * BN;

  const int ntiles = K >> 6;
  const int NT2 = ntiles >> 1;

  auto sA = [&](int buf, int tile, int half, int issue) {
    if (tile >= ntiles) return;
    const int R0 = half * 64 + issue * 128;
    const int rr = R0 + w * 8 + (lane >> 3);
    const int sl = lane & 7;
    const bf16* src = A + (size_t)(m0 + rr) * K + tile * 64 + ((sl ^ (rr & 7)) * 8);
    gload_lds16(src, As_[buf] + (R0 + w * 8) * 128);
  };
  auto sB = [&](int buf, int tile, int half, int issue) {
    if (tile >= ntiles) return;
    const int slot = issue * 8 + w;
    const int per = (half ? NH1 : NH0) * 2;
    const int wng = slot / per, within = slot % per;
    const int block = wng * (NR * 2) + (half ? NH0 * 2 : 0) + within;
    const int rr = block * 8 + (lane >> 3);
    const int sl = lane & 7;
    const bf16* src = Bt + (size_t)(n0 + rr) * K + tile * 64 + ((sl ^ (rr & 7)) * 8);
    gload_lds16(src, Bs_[buf] + block * 1024);
  };
  auto sBh = [&](int buf, int tile, int half) {
    sB(buf, tile, half, 0);
    if ((half ? NH1 : NH0) == 2) sB(buf, tile, half, 1);
  };

  const int swz0 = (g ^ (li & 7)) * 16;
  const int swz1 = ((4 + g) ^ (li & 7)) * 16;
  bf16x8 af[8], b0v[NH0 * 2], b1v[NH1 * 2];
  f32x4 acc[8][NR] = {};

  auto readA = [&](int buf, int mh) {
#pragma unroll
    for (int m = 0; m < 4; ++m) {
      const char* p = As_[buf] + (wm * 128 + mh * 64 + m * 16 + li) * 128;
      af[m * 2 + 0] = *(const bf16x8*)(p + swz0);
      af[m * 2 + 1] = *(const bf16x8*)(p + swz1);
    }
  };
  auto readB0 = [&](int buf) {
#pragma unroll
    for (int n = 0; n < NH0; ++n) {
      const char* p = Bs_[buf] + (wn * (NR * 16) + n * 16 + li) * 128;
      b0v[n * 2 + 0] = *(const bf16x8*)(p + swz0);
      b0v[n * 2 + 1] = *(const bf16x8*)(p + swz1);
    }
  };
  auto readB1 = [&](int buf) {
#pragma unroll
    for (int n = 0; n < NH1; ++n) {
      const char* p = Bs_[buf] + (wn * (NR * 16) + NH0 * 16 + n * 16 + li) * 128;
      b1v[n * 2 + 0] = *(const bf16x8*)(p + swz0);
      b1v[n * 2 + 1] = *(const bf16x8*)(p + swz1);
    }
  };
  auto MMA0 = [&](int mh) {
    __builtin_amdgcn_s_setprio(1);
#pragma unroll
    for (int m = 0; m < 4; ++m)
#pragma unroll
      for (int n = 0; n < NH0; ++n)
#pragma unroll
        for (int kk = 0; kk < 2; ++kk)
          acc[mh * 4 + m][n] = __builtin_amdgcn_mfma_f32_16x16x32_bf16(
              af[m * 2 + kk], b0v[n * 2 + kk], acc[mh * 4 + m][n], 0, 0, 0);
    __builtin_amdgcn_s_setprio(0);
  };
  auto MMA1 = [&](int mh) {
    __builtin_amdgcn_s_setprio(1);
#pragma unroll
    for (int m = 0; m < 4; ++m)
#pragma unroll
      for (int n = 0; n < NH1; ++n)
#pragma unroll
        for (int kk = 0; kk < 2; ++kk)
          acc[mh * 4 + m][NH0 + n] = __builtin_amdgcn_mfma_f32_16x16x32_bf16(
              af[m * 2 + kk], b1v[n * 2 + kk], acc[mh * 4 + m][NH0 + n], 0, 0, 0);
    __builtin_amdgcn_s_setprio(0);
  };
  auto VMW = [&](bool last) {
    if (last) {
      asm volatile("s_waitcnt vmcnt(0)" ::: "memory");
    } else {
      if constexpr (VMN == 4)
        asm volatile("s_waitcnt vmcnt(4)" ::: "memory");
      else
        asm volatile("s_waitcnt vmcnt(3)" ::: "memory");
    }
    __builtin_amdgcn_sched_barrier(0);
  };

  // ---- prologue: tile0 full + tile1 A0/B0; wait tile0 ----
  sA(0, 0, 0, 0); sA(0, 0, 0, 1); sA(0, 0, 1, 0); sA(0, 0, 1, 1);
  sBh(0, 0, 0); sBh(0, 0, 1);
  sA(1, 1, 0, 0); sA(1, 1, 0, 1);
  sBh(1, 1, 0);
  if constexpr (VMN == 4)
    asm volatile("s_waitcnt vmcnt(4)" ::: "memory");
  else
    asm volatile("s_waitcnt vmcnt(3)" ::: "memory");
  __builtin_amdgcn_sched_barrier(0);
  FBAR();

  for (int itr = 0; itr < NT2; ++itr) {
    const int t = itr * 2;
    const bool last = (itr == NT2 - 1);
    // ph1: tile t (buf0) M0N0; stage (t+1).A1 -> buf1
    readA(0, 0); readB0(0);
    sA(1, t + 1, 1, 0); sA(1, t + 1, 1, 1);
    FBAR(); MMA0(0); FBAR();
    // ph2: M0N1; stage (t+1).B1
    readB1(0);
    sBh(1, t + 1, 1);
    FBAR(); MMA1(0); FBAR();
    // ph3: M1N0; stage (t+2).A0 -> buf0
    readA(0, 1);
    sA(0, t + 2, 0, 0); sA(0, t + 2, 0, 1);
    FBAR(); MMA0(1); FBAR();
    // ph4: M1N1; stage (t+2).B0; counted vmcnt
    sBh(0, t + 2, 0);
    VMW(last);
    FBAR(); MMA1(1); FBAR();
    // ph5: tile t+1 (buf1) M0N0; stage (t+2).A1
    readA(1, 0); readB0(1);
    sA(0, t + 2, 1, 0); sA(0, t + 2, 1, 1);
    FBAR(); MMA0(0); FBAR();
    // ph6: M0N1; stage (t+2).B1
    readB1(1);
    sBh(0, t + 2, 1);
    FBAR(); MMA1(0); FBAR();
    // ph7: M1N0; stage (t+3).A0 -> buf1
    readA(1, 1);
    sA(1, t + 3, 0, 0); sA(1, t + 3, 0, 1);
    FBAR(); MMA0(1); FBAR();
    // ph8: M1N1; stage (t+3).B0; counted vmcnt
    sBh(1, t + 3, 0);
    VMW(last);
    FBAR(); MMA1(1); FBAR();
  }

#pragma unroll
  for (int mf = 0; mf < 8; ++mf)
#pragma unroll
    for (int nf = 0; nf < NR; ++nf)
#pragma unroll
      for (int r = 0; r < 4; ++r) {
        int row = m0 + wm * 128 + mf * 16 + g * 4 + r;
        int col = n0 + wn * (NR * 16) + nf * 16 + li;
        float v = acc[mf][nf][r];
        if constexpr (OUT_BF16)
          ((bf16*)Cout)[(size_t)row * N + col] = __float2bfloat16(v);
        else
          ((float*)Cout)[(size_t)row * N + col] = v;
      }
}

// ---------------- RoPE over fused qkv (in place) + V->V^T, one launch ------
// blocks [0,20480): rope (q heads pre-scaled); [20480,20992): vtrans
__global__ __launch_bounds__(256) void k_rope_vtrans(bf16* __restrict__ qkv,
                                                     const float* __restrict__ cosT,
                                                     const float* __restrict__ sinT,
                                                     bf16* __restrict__ vt) {
  int id = blockIdx.x;
  int tid = threadIdx.x;
  if (id < 20480) {
    int p = id * 256 + tid;
    int i = p & 63;
    int h20 = (p >> 6) % 20;
    int bt = p / (64 * 20);
    int t = bt & (T_ - 1);
    float c = cosT[t * 64 + i], s = sinT[t * 64 + i];
    bool isq = h20 < 16;
    int col = isq ? h20 * DH : DM + (h20 - 16) * DH;
    float sc = isq ? 0.08838834764831845f : 1.0f;  // fold 1/sqrt(128) into Q
    size_t base = (size_t)bt * 3072 + col + 2 * i;
    float tr = __bfloat162float(qkv[base]);
    float ti = __bfloat162float(qkv[base + 1]);
    qkv[base] = __float2bfloat16((tr * c - ti * s) * sc);
    qkv[base + 1] = __float2bfloat16((tr * s + ti * c) * sc);
    return;
  }
  int v = id - 20480;
  __shared__ bf16 tile[64][72];
  int bt0 = (v & 63) * 64, c0 = (v >> 6) * 64;
  int tx = tid & 63, tg = tid >> 6;
#pragma unroll
  for (int r = 0; r < 16; ++r) {
    int row = tg * 16 + r;
    tile[row][tx] = qkv[(size_t)(bt0 + row) * 3072 + 2560 + c0 + tx];
  }
  __syncthreads();
#pragma unroll
  for (int r = 0; r < 16; ++r) {
    int row2 = tg * 16 + r;
    vt[(size_t)(c0 + row2) * (B_ * T_) + bt0 + tx] = tile[tx][row2];
  }
}

// ---------------- windowed flash attention, swapped QK^T ----------------
__global__ __launch_bounds__(512) void k_attn(const bf16* __restrict__ qkv,
                                              const bf16* __restrict__ vt,
                                              bf16* __restrict__ Y) {
  __shared__ __align__(16) char Ks[2][9216];
  __shared__ __align__(16) char Vs[2][10240];
  __shared__ __align__(16) char Pl[8][1280];
  const int lane = threadIdx.x & 63;
  const int w = threadIdx.x >> 6;
  const int li = lane & 15, g = lane >> 4;
  const int t0 = ((int)gridDim.x - 1 - (int)blockIdx.x) * 32;
  const int b = blockIdx.y / NKV, kvh = blockIdx.y % NKV;
  const int h = kvh * 4 + (w >> 1);
  const int qrow0 = t0 + (w & 1) * 16;
  const int t = qrow0 + li;

  bf16x8 qf[4];
  const bf16* qbase = qkv + (size_t)(b * T_ + qrow0 + li) * 3072 + h * DH;
#pragma unroll
  for (int dk = 0; dk < 4; ++dk) qf[dk] = *(const bf16x8*)(qbase + dk * 32 + g * 8);

  float mrow = -1e4f;
  float srow = 0.f;
  f32x4 acc[8] = {};

  int ks0 = t0 - (WIN - 1);
  if (ks0 < 0) ks0 = 0;
  ks0 &= ~31;
  const int nt = (t0 + 31 - ks0) / 32 + 1;

  const bf16* kgbase = qkv + (size_t)(b * T_) * 3072 + DM + kvh * DH;
  const bf16* vgbase = vt + (size_t)(kvh * DH) * (B_ * T_) + b * T_;

  auto STAGE = [&](int buf, int kt) {
    for (int c = w; c < 19; c += 8) {
      if (c < 9) {
        int slot = c * 64 + lane;
        int row = slot / 17, cc = slot % 17;
        if (slot >= 544) { row = 0; cc = 0; }
        if (cc == 16) cc = 0;
        const bf16* src = kgbase + (size_t)(kt + row) * 3072 + cc * 8;
        gload_lds16(src, Ks[buf] + c * 1024);
      } else {
        int c2 = c - 9;
        int slot = c2 * 64 + lane;
        int row = slot / 5, cc = slot % 5;
        if (cc == 4) cc = 0;
        const bf16* src = vgbase + (size_t)row * (B_ * T_) + kt + cc * 8;
        gload_lds16(src, Vs[buf] + c2 * 1024);
      }
    }
  };

  STAGE(0, ks0);
  __syncthreads();
  int cur = 0;

  for (int it = 0; it < nt; ++it) {
    const int kt = ks0 + it * 32;
    if (it + 1 < nt) STAGE(cur ^ 1, kt + 32);

    f32x4 sc[2] = {};
#pragma unroll
    for (int n = 0; n < 2; ++n)
#pragma unroll
      for (int dk = 0; dk < 4; ++dk) {
        bf16x8 kf = *(const bf16x8*)(Ks[cur] + (n * 16 + li) * 272 + dk * 64 + g * 16);
        sc[n] = __builtin_amdgcn_mfma_f32_16x16x32_bf16(kf, qf[dk], sc[n], 0, 0, 0);
      }

    float p[2][4];
    float pmax = -1e30f;
#pragma unroll
    for (int n = 0; n < 2; ++n)
#pragma unroll
      for (int r = 0; r < 4; ++r) {
        int key = kt + n * 16 + g * 4 + r;
        bool valid = (key <= t) && (key > t - WIN);
        float pv = valid ? sc[n][r] : -1e30f;
        p[n][r] = pv;
        pmax = fmaxf(pmax, pv);
      }
    pmax = fmaxf(pmax, __shfl_xor(pmax, 16));
    pmax = fmaxf(pmax, __shfl_xor(pmax, 32));

    float nm = fmaxf(mrow, pmax);
    float alpha = __expf(mrow - nm);
    mrow = nm;
    float rs = 0.f;
#pragma unroll
    for (int n = 0; n < 2; ++n)
#pragma unroll
      for (int r = 0; r < 4; ++r) {
        p[n][r] = __expf(p[n][r] - nm);
        rs += p[n][r];
      }
    rs += __shfl_xor(rs, 16);
    rs += __shfl_xor(rs, 32);
    srow = srow * alpha + rs;

#pragma unroll
    for (int n = 0; n < 2; ++n) {
      *(unsigned*)(Pl[w] + li * 80 + n * 32 + g * 8) = pack_bf2(p[n][0], p[n][1]);
      *(unsigned*)(Pl[w] + li * 80 + n * 32 + g * 8 + 4) = pack_bf2(p[n][2], p[n][3]);
    }

    float af_[4];
#pragma unroll
    for (int r = 0; r < 4; ++r) af_[r] = __shfl(alpha, (g << 2) + r);
#pragma unroll
    for (int db = 0; db < 8; ++db)
#pragma unroll
      for (int r = 0; r < 4; ++r) acc[db][r] *= af_[r];

    bf16x8 pf = *(const bf16x8*)(Pl[w] + li * 80 + g * 16);
#pragma unroll
    for (int db = 0; db < 8; ++db) {
      bf16x8 vf = *(const bf16x8*)(Vs[cur] + (db * 16 + li) * 80 + g * 16);
      acc[db] = __builtin_amdgcn_mfma_f32_16x16x32_bf16(pf, vf, acc[db], 0, 0, 0);
    }

    __syncthreads();
    cur ^= 1;
  }

  float inv[4];
#pragma unroll
  for (int r = 0; r < 4; ++r) inv[r] = 1.f / __shfl(srow, (g << 2) + r);
  bf16* ybase = Y + (size_t)(b * T_ + qrow0 + (g << 2)) * DM + h * DH;
#pragma unroll
  for (int r = 0; r < 4; ++r)
#pragma unroll
    for (int db = 0; db < 8; ++db)
      ybase[(size_t)r * DM + db * 16 + li] = __float2bfloat16(acc[db][r] * inv[r]);
}

extern "C" void kernel_launch(void* const* d_in, const int* in_sizes, int n_in,
                              void* d_out, int out_size, void* d_ws, size_t ws_size,
                              hipStream_t stream) {
  const float* x = (const float*)d_in[0];
  const float* cosT = (const float*)d_in[1];
  const float* sinT = (const float*)d_in[2];
  const float* Wq = (const float*)d_in[3];
  const float* Wk = (const float*)d_in[4];
  const float* Wv = (const float*)d_in[5];
  const float* Wo = (const float*)d_in[6];
  float* out = (float*)d_out;

  char* ws = (char*)d_ws;
  bf16* xb = (bf16*)ws;     ws += (size_t)4096 * 2048 * 2;
  bf16* Wqkvt = (bf16*)ws;  ws += (size_t)3072 * 2048 * 2;
  bf16* Wot = (bf16*)ws;    ws += (size_t)2048 * 2048 * 2;
  bf16* qkv = (bf16*)ws;    ws += (size_t)4096 * 3072 * 2;
  bf16* yb = xb;
  bf16* vt = Wqkvt;

  k_prep<<<4608, 256, 0, stream>>>(x, Wq, Wk, Wv, Wo, xb, Wqkvt, Wot);

  k_gemm8<192, true><<<dim3(3072 / 192, 4096 / 256), 512, 0, stream>>>(xb, Wqkvt, qkv, 4096, 3072, 2048);

  k_rope_vtrans<<<20992, 256, 0, stream>>>(qkv, cosT, sinT, vt);

  k_attn<<<dim3(T_ / 32, B_ * NKV), 512, 0, stream>>>(qkv, vt, yb);

  k_gemm8<128, false><<<dim3(2048 / 128, 4096 / 256), 512, 0, stream>>>(yb, Wot, out, 4096, 2048, 2048);
}

// Round 7
// 164.680 us; speedup vs baseline: 2.2604x; 1.0429x over previous
//
#include <hip/hip_runtime.h>
#include <hip/hip_bf16.h>
#include <cstdint>
#include <cstddef>

#define B_ 2
#define T_ 2048
#define NH 16
#define NKV 4
#define DH 128
#define DM 2048
#define WIN 512
#define QKS 2560  // qkv row stride (q 2048 | k 512); v goes straight to vt

typedef __attribute__((ext_vector_type(4))) float f32x4;
typedef __attribute__((ext_vector_type(8))) __bf16 bf16x8;

using bf16 = __hip_bfloat16;

__device__ inline void gload_lds16(const void* g, void* l) {
  __builtin_amdgcn_global_load_lds(
      (const __attribute__((address_space(1))) void*)g,
      (__attribute__((address_space(3))) void*)l, 16, 0, 0);
}

__device__ inline unsigned pack_bf2(float a, float b) {
  unsigned short ua = __builtin_bit_cast(unsigned short, __float2bfloat16(a));
  unsigned short ub = __builtin_bit_cast(unsigned short, __float2bfloat16(b));
  return (unsigned)ua | ((unsigned)ub << 16);
}

#define FBAR()                           \
  do {                                   \
    asm volatile("" ::: "memory");       \
    __builtin_amdgcn_s_barrier();        \
    asm volatile("" ::: "memory");       \
  } while (0)

// ---------------- prep: x fp32->bf16 + all weight transposes ----------------
__global__ __launch_bounds__(256) void k_prep(const float* __restrict__ x,
                                              const float* __restrict__ Wq,
                                              const float* __restrict__ Wk,
                                              const float* __restrict__ Wv,
                                              const float* __restrict__ Wo,
                                              bf16* __restrict__ xb,
                                              bf16* __restrict__ Wqkvt,
                                              bf16* __restrict__ Wot) {
  int id = blockIdx.x;
  int tid = threadIdx.x;
  if (id >= 2560) {  // convert
    size_t base = (size_t)(id - 2560) * 4096 + tid * 16;
#pragma unroll
    for (int j = 0; j < 4; ++j) {
      float4 v = *(const float4*)(x + base + j * 4);
      ushort4 o;
      o.x = __builtin_bit_cast(unsigned short, __float2bfloat16(v.x));
      o.y = __builtin_bit_cast(unsigned short, __float2bfloat16(v.y));
      o.z = __builtin_bit_cast(unsigned short, __float2bfloat16(v.z));
      o.w = __builtin_bit_cast(unsigned short, __float2bfloat16(v.w));
      *(ushort4*)(xb + base + j * 4) = o;
    }
    return;
  }
  const float* W;
  bf16* Wt;
  int N, bx, by;
  if (id < 1024) { W = Wq; Wt = Wqkvt; N = 2048; bx = id & 31; by = id >> 5; }
  else if (id < 1280) { id -= 1024; W = Wk; Wt = Wqkvt + (size_t)2048 * 2048; N = 512; bx = id & 7; by = id >> 3; }
  else if (id < 1536) { id -= 1280; W = Wv; Wt = Wqkvt + (size_t)2560 * 2048; N = 512; bx = id & 7; by = id >> 3; }
  else { id -= 1536; W = Wo; Wt = Wot; N = 2048; bx = id & 31; by = id >> 5; }

  __shared__ float tile[64][65];
  int n0 = bx * 64, k0 = by * 64;
  int tx = tid & 63, tg = tid >> 6;
#pragma unroll
  for (int r = 0; r < 16; ++r) {
    int k = tg * 16 + r;
    tile[k][tx] = W[(size_t)(k0 + k) * N + n0 + tx];
  }
  __syncthreads();
#pragma unroll
  for (int r = 0; r < 16; ++r) {
    int nn = tg * 16 + r;
    Wt[(size_t)(n0 + nn) * 2048 + k0 + tx] = __float2bfloat16(tile[tx][nn]);
  }
}

// ======== 256-row 8-phase MFMA GEMM: C[M][N] = A[M][K] * Bt[N][K]^T ========
// EPI: 0 = fp32 C, 1 = bf16 C, 2 = fused qkv epilogue (rope q/k, v->vt^T)
template <int BN, int EPI>
__global__ __launch_bounds__(512, 2) void k_gemm8(const bf16* __restrict__ A,
                                                  const bf16* __restrict__ Bt,
                                                  void* __restrict__ Cout,
                                                  int M, int N, int K,
                                                  const float* __restrict__ cosT,
                                                  const float* __restrict__ sinT,
                                                  bf16* __restrict__ vt) {
  constexpr int NR = BN / 64;          // n-frags per wave
  constexpr int NH0 = (NR + 1) / 2;    // frags in N-half0
  constexpr int NH1 = NR - NH0;        // frags in N-half1
  constexpr int VMN = 2 + NH0;         // counted vmcnt
  __shared__ __align__(16) char As_[2][32768];
  __shared__ __align__(16) char Bs_[2][BN * 128];

  const int tid = threadIdx.x;
  const int w = tid >> 6, lane = tid & 63;
  const int li = lane & 15, g = lane >> 4;
  const int wm = w >> 2, wn = w & 3;

  const int nwg = gridDim.x * gridDim.y;
  int bid = blockIdx.y * gridDim.x + blockIdx.x;
  bid = (bid & 7) * (nwg >> 3) + (bid >> 3);
  const int m0 = (bid / gridDim.x) * 256;
  const int n0 = (bid % gridDim.x) * BN;

  const int ntiles = K >> 6;
  const int NT2 = ntiles >> 1;

  auto sA = [&](int buf, int tile, int half, int issue) {
    if (tile >= ntiles) return;
    const int R0 = half * 64 + issue * 128;
    const int rr = R0 + w * 8 + (lane >> 3);
    const int sl = lane & 7;
    const bf16* src = A + (size_t)(m0 + rr) * K + tile * 64 + ((sl ^ (rr & 7)) * 8);
    gload_lds16(src, As_[buf] + (R0 + w * 8) * 128);
  };
  auto sB = [&](int buf, int tile, int half, int issue) {
    if (tile >= ntiles) return;
    const int slot = issue * 8 + w;
    const int per = (half ? NH1 : NH0) * 2;
    const int wng = slot / per, within = slot % per;
    const int block = wng * (NR * 2) + (half ? NH0 * 2 : 0) + within;
    const int rr = block * 8 + (lane >> 3);
    const int sl = lane & 7;
    const bf16* src = Bt + (size_t)(n0 + rr) * K + tile * 64 + ((sl ^ (rr & 7)) * 8);
    gload_lds16(src, Bs_[buf] + block * 1024);
  };
  auto sBh = [&](int buf, int tile, int half) {
    sB(buf, tile, half, 0);
    if ((half ? NH1 : NH0) == 2) sB(buf, tile, half, 1);
  };

  const int swz0 = (g ^ (li & 7)) * 16;
  const int swz1 = ((4 + g) ^ (li & 7)) * 16;
  bf16x8 af[8], b0v[NH0 * 2], b1v[NH1 * 2];
  f32x4 acc[8][NR] = {};

  auto readA = [&](int buf, int mh) {
#pragma unroll
    for (int m = 0; m < 4; ++m) {
      const char* p = As_[buf] + (wm * 128 + mh * 64 + m * 16 + li) * 128;
      af[m * 2 + 0] = *(const bf16x8*)(p + swz0);
      af[m * 2 + 1] = *(const bf16x8*)(p + swz1);
    }
  };
  auto readB0 = [&](int buf) {
#pragma unroll
    for (int n = 0; n < NH0; ++n) {
      const char* p = Bs_[buf] + (wn * (NR * 16) + n * 16 + li) * 128;
      b0v[n * 2 + 0] = *(const bf16x8*)(p + swz0);
      b0v[n * 2 + 1] = *(const bf16x8*)(p + swz1);
    }
  };
  auto readB1 = [&](int buf) {
#pragma unroll
    for (int n = 0; n < NH1; ++n) {
      const char* p = Bs_[buf] + (wn * (NR * 16) + NH0 * 16 + n * 16 + li) * 128;
      b1v[n * 2 + 0] = *(const bf16x8*)(p + swz0);
      b1v[n * 2 + 1] = *(const bf16x8*)(p + swz1);
    }
  };
  auto MMA0 = [&](int mh) {
    __builtin_amdgcn_s_setprio(1);
#pragma unroll
    for (int m = 0; m < 4; ++m)
#pragma unroll
      for (int n = 0; n < NH0; ++n)
#pragma unroll
        for (int kk = 0; kk < 2; ++kk)
          acc[mh * 4 + m][n] = __builtin_amdgcn_mfma_f32_16x16x32_bf16(
              af[m * 2 + kk], b0v[n * 2 + kk], acc[mh * 4 + m][n], 0, 0, 0);
    __builtin_amdgcn_s_setprio(0);
  };
  auto MMA1 = [&](int mh) {
    __builtin_amdgcn_s_setprio(1);
#pragma unroll
    for (int m = 0; m < 4; ++m)
#pragma unroll
      for (int n = 0; n < NH1; ++n)
#pragma unroll
        for (int kk = 0; kk < 2; ++kk)
          acc[mh * 4 + m][NH0 + n] = __builtin_amdgcn_mfma_f32_16x16x32_bf16(
              af[m * 2 + kk], b1v[n * 2 + kk], acc[mh * 4 + m][NH0 + n], 0, 0, 0);
    __builtin_amdgcn_s_setprio(0);
  };
  auto VMW = [&](bool last) {
    if (last) {
      asm volatile("s_waitcnt vmcnt(0)" ::: "memory");
    } else {
      if constexpr (VMN == 4)
        asm volatile("s_waitcnt vmcnt(4)" ::: "memory");
      else
        asm volatile("s_waitcnt vmcnt(3)" ::: "memory");
    }
    __builtin_amdgcn_sched_barrier(0);
  };

  sA(0, 0, 0, 0); sA(0, 0, 0, 1); sA(0, 0, 1, 0); sA(0, 0, 1, 1);
  sBh(0, 0, 0); sBh(0, 0, 1);
  sA(1, 1, 0, 0); sA(1, 1, 0, 1);
  sBh(1, 1, 0);
  if constexpr (VMN == 4)
    asm volatile("s_waitcnt vmcnt(4)" ::: "memory");
  else
    asm volatile("s_waitcnt vmcnt(3)" ::: "memory");
  __builtin_amdgcn_sched_barrier(0);
  FBAR();

  for (int itr = 0; itr < NT2; ++itr) {
    const int t = itr * 2;
    const bool last = (itr == NT2 - 1);
    readA(0, 0); readB0(0);
    sA(1, t + 1, 1, 0); sA(1, t + 1, 1, 1);
    FBAR(); MMA0(0); FBAR();
    readB1(0);
    sBh(1, t + 1, 1);
    FBAR(); MMA1(0); FBAR();
    readA(0, 1);
    sA(0, t + 2, 0, 0); sA(0, t + 2, 0, 1);
    FBAR(); MMA0(1); FBAR();
    sBh(0, t + 2, 0);
    VMW(last);
    FBAR(); MMA1(1); FBAR();
    readA(1, 0); readB0(1);
    sA(0, t + 2, 1, 0); sA(0, t + 2, 1, 1);
    FBAR(); MMA0(0); FBAR();
    readB1(1);
    sBh(0, t + 2, 1);
    FBAR(); MMA1(0); FBAR();
    readA(1, 1);
    sA(1, t + 3, 0, 0); sA(1, t + 3, 0, 1);
    FBAR(); MMA0(1); FBAR();
    sBh(1, t + 3, 0);
    VMW(last);
    FBAR(); MMA1(1); FBAR();
  }

  // ---------------- epilogue ----------------
#pragma unroll
  for (int mf = 0; mf < 8; ++mf)
#pragma unroll
    for (int nf = 0; nf < NR; ++nf) {
      const int colc = n0 + wn * (NR * 16) + nf * 16;  // wave-uniform chunk base
      const int col = colc + li;
      const int row0 = m0 + wm * 128 + mf * 16 + g * 4;
      if constexpr (EPI == 2) {
        if (colc < QKS) {  // q or k: rope (q additionally pre-scaled)
          const float qs = (colc < 2048) ? 0.08838834764831845f : 1.0f;
          const int i = (col & 127) >> 1;
          const float sgn = (li & 1) ? 1.0f : -1.0f;
#pragma unroll
          for (int r = 0; r < 4; ++r) {
            const int trow = (row0 + r) & (T_ - 1);
            float v = acc[mf][nf][r];
            float pv = __shfl_xor(v, 1);
            float c = cosT[trow * 64 + i], s = sinT[trow * 64 + i];
            float o = (v * c + pv * (sgn * s)) * qs;
            ((bf16*)Cout)[(size_t)(row0 + r) * QKS + col] = __float2bfloat16(o);
          }
        } else {  // v: write transposed into vt[col-2560][row], 4 rows packed
          unsigned lo = pack_bf2(acc[mf][nf][0], acc[mf][nf][1]);
          unsigned hi = pack_bf2(acc[mf][nf][2], acc[mf][nf][3]);
          uint2 pk = {lo, hi};
          *(uint2*)(vt + (size_t)(col - QKS) * (B_ * T_) + row0) = pk;
        }
      } else {
#pragma unroll
        for (int r = 0; r < 4; ++r) {
          float v = acc[mf][nf][r];
          if constexpr (EPI == 1)
            ((bf16*)Cout)[(size_t)(row0 + r) * N + col] = __float2bfloat16(v);
          else
            ((float*)Cout)[(size_t)(row0 + r) * N + col] = v;
        }
      }
    }
}

// ---------------- windowed flash attention, swapped QK^T ----------------
__global__ __launch_bounds__(512) void k_attn(const bf16* __restrict__ qkv,
                                              const bf16* __restrict__ vt,
                                              bf16* __restrict__ Y) {
  __shared__ __align__(16) char Ks[2][9216];
  __shared__ __align__(16) char Vs[2][10240];
  __shared__ __align__(16) char Pl[8][1280];
  const int lane = threadIdx.x & 63;
  const int w = threadIdx.x >> 6;
  const int li = lane & 15, g = lane >> 4;
  const int t0 = ((int)gridDim.x - 1 - (int)blockIdx.x) * 32;
  const int b = blockIdx.y / NKV, kvh = blockIdx.y % NKV;
  const int h = kvh * 4 + (w >> 1);
  const int qrow0 = t0 + (w & 1) * 16;
  const int t = qrow0 + li;

  bf16x8 qf[4];
  const bf16* qbase = qkv + (size_t)(b * T_ + qrow0 + li) * QKS + h * DH;
#pragma unroll
  for (int dk = 0; dk < 4; ++dk) qf[dk] = *(const bf16x8*)(qbase + dk * 32 + g * 8);

  float mrow = -1e4f;
  float srow = 0.f;
  f32x4 acc[8] = {};

  int ks0 = t0 - (WIN - 1);
  if (ks0 < 0) ks0 = 0;
  ks0 &= ~31;
  const int nt = (t0 + 31 - ks0) / 32 + 1;

  const bf16* kgbase = qkv + (size_t)(b * T_) * QKS + DM + kvh * DH;
  const bf16* vgbase = vt + (size_t)(kvh * DH) * (B_ * T_) + b * T_;

  auto STAGE = [&](int buf, int kt) {
    for (int c = w; c < 19; c += 8) {
      if (c < 9) {
        int slot = c * 64 + lane;
        int row = slot / 17, cc = slot % 17;
        if (slot >= 544) { row = 0; cc = 0; }
        if (cc == 16) cc = 0;
        const bf16* src = kgbase + (size_t)(kt + row) * QKS + cc * 8;
        gload_lds16(src, Ks[buf] + c * 1024);
      } else {
        int c2 = c - 9;
        int slot = c2 * 64 + lane;
        int row = slot / 5, cc = slot % 5;
        if (cc == 4) cc = 0;
        const bf16* src = vgbase + (size_t)row * (B_ * T_) + kt + cc * 8;
        gload_lds16(src, Vs[buf] + c2 * 1024);
      }
    }
  };

  STAGE(0, ks0);
  __syncthreads();
  int cur = 0;

  for (int it = 0; it < nt; ++it) {
    const int kt = ks0 + it * 32;
    if (it + 1 < nt) STAGE(cur ^ 1, kt + 32);

    f32x4 sc[2] = {};
#pragma unroll
    for (int n = 0; n < 2; ++n)
#pragma unroll
      for (int dk = 0; dk < 4; ++dk) {
        bf16x8 kf = *(const bf16x8*)(Ks[cur] + (n * 16 + li) * 272 + dk * 64 + g * 16);
        sc[n] = __builtin_amdgcn_mfma_f32_16x16x32_bf16(kf, qf[dk], sc[n], 0, 0, 0);
      }

    float p[2][4];
    float pmax = -1e30f;
#pragma unroll
    for (int n = 0; n < 2; ++n)
#pragma unroll
      for (int r = 0; r < 4; ++r) {
        int key = kt + n * 16 + g * 4 + r;
        bool valid = (key <= t) && (key > t - WIN);
        float pv = valid ? sc[n][r] : -1e30f;
        p[n][r] = pv;
        pmax = fmaxf(pmax, pv);
      }
    pmax = fmaxf(pmax, __shfl_xor(pmax, 16));
    pmax = fmaxf(pmax, __shfl_xor(pmax, 32));

    // T13 defer-rescale: only rescale when the running max actually grows
    if (!__all(pmax <= mrow)) {
      float nm = fmaxf(mrow, pmax);
      float alpha = __expf(mrow - nm);
      mrow = nm;
      srow *= alpha;
      float af_[4];
#pragma unroll
      for (int r = 0; r < 4; ++r) af_[r] = __shfl(alpha, (g << 2) + r);
#pragma unroll
      for (int db = 0; db < 8; ++db)
#pragma unroll
        for (int r = 0; r < 4; ++r) acc[db][r] *= af_[r];
    }

    float rs = 0.f;
#pragma unroll
    for (int n = 0; n < 2; ++n)
#pragma unroll
      for (int r = 0; r < 4; ++r) {
        p[n][r] = __expf(p[n][r] - mrow);
        rs += p[n][r];
      }
    rs += __shfl_xor(rs, 16);
    rs += __shfl_xor(rs, 32);
    srow += rs;

#pragma unroll
    for (int n = 0; n < 2; ++n) {
      *(unsigned*)(Pl[w] + li * 80 + n * 32 + g * 8) = pack_bf2(p[n][0], p[n][1]);
      *(unsigned*)(Pl[w] + li * 80 + n * 32 + g * 8 + 4) = pack_bf2(p[n][2], p[n][3]);
    }

    bf16x8 pf = *(const bf16x8*)(Pl[w] + li * 80 + g * 16);
#pragma unroll
    for (int db = 0; db < 8; ++db) {
      bf16x8 vf = *(const bf16x8*)(Vs[cur] + (db * 16 + li) * 80 + g * 16);
      acc[db] = __builtin_amdgcn_mfma_f32_16x16x32_bf16(pf, vf, acc[db], 0, 0, 0);
    }

    __syncthreads();
    cur ^= 1;
  }

  float inv[4];
#pragma unroll
  for (int r = 0; r < 4; ++r) inv[r] = 1.f / __shfl(srow, (g << 2) + r);
  bf16* ybase = Y + (size_t)(b * T_ + qrow0 + (g << 2)) * DM + h * DH;
#pragma unroll
  for (int r = 0; r < 4; ++r)
#pragma unroll
    for (int db = 0; db < 8; ++db)
      ybase[(size_t)r * DM + db * 16 + li] = __float2bfloat16(acc[db][r] * inv[r]);
}

extern "C" void kernel_launch(void* const* d_in, const int* in_sizes, int n_in,
                              void* d_out, int out_size, void* d_ws, size_t ws_size,
                              hipStream_t stream) {
  const float* x = (const float*)d_in[0];
  const float* cosT = (const float*)d_in[1];
  const float* sinT = (const float*)d_in[2];
  const float* Wq = (const float*)d_in[3];
  const float* Wk = (const float*)d_in[4];
  const float* Wv = (const float*)d_in[5];
  const float* Wo = (const float*)d_in[6];
  float* out = (float*)d_out;

  char* ws = (char*)d_ws;
  bf16* xb = (bf16*)ws;     ws += (size_t)4096 * 2048 * 2;   // 16.8 MB (reused as yb)
  bf16* Wqkvt = (bf16*)ws;  ws += (size_t)3072 * 2048 * 2;   // 12.6 MB
  bf16* Wot = (bf16*)ws;    ws += (size_t)2048 * 2048 * 2;   // 8.4 MB
  bf16* qkv = (bf16*)ws;    ws += (size_t)4096 * QKS * 2;    // 21.0 MB (q|k only)
  bf16* vt = (bf16*)ws;     ws += (size_t)512 * 4096 * 2;    // 4.2 MB (V^T)
  bf16* yb = xb;

  k_prep<<<4608, 256, 0, stream>>>(x, Wq, Wk, Wv, Wo, xb, Wqkvt, Wot);

  k_gemm8<192, 2><<<dim3(3072 / 192, 4096 / 256), 512, 0, stream>>>(
      xb, Wqkvt, qkv, 4096, 3072, 2048, cosT, sinT, vt);

  k_attn<<<dim3(T_ / 32, B_ * NKV), 512, 0, stream>>>(qkv, vt, yb);

  k_gemm8<128, 0><<<dim3(2048 / 128, 4096 / 256), 512, 0, stream>>>(
      yb, Wot, out, 4096, 2048, 2048, nullptr, nullptr, nullptr);
}

// Round 8
// 156.829 us; speedup vs baseline: 2.3736x; 1.0501x over previous
//
#include <hip/hip_runtime.h>
#include <hip/hip_bf16.h>
#include <cstdint>
#include <cstddef>

#define B_ 2
#define T_ 2048
#define NH 16
#define NKV 4
#define DH 128
#define DM 2048
#define WIN 512
#define QKS 2560  // qkv row stride (q 2048 | k 512); v goes straight to vt

typedef __attribute__((ext_vector_type(4))) float f32x4;
typedef __attribute__((ext_vector_type(8))) __bf16 bf16x8;

using bf16 = __hip_bfloat16;

__device__ inline void gload_lds16(const void* g, void* l) {
  __builtin_amdgcn_global_load_lds(
      (const __attribute__((address_space(1))) void*)g,
      (__attribute__((address_space(3))) void*)l, 16, 0, 0);
}

__device__ inline unsigned pack_bf2(float a, float b) {
  unsigned short ua = __builtin_bit_cast(unsigned short, __float2bfloat16(a));
  unsigned short ub = __builtin_bit_cast(unsigned short, __float2bfloat16(b));
  return (unsigned)ua | ((unsigned)ub << 16);
}

#define FBAR()                           \
  do {                                   \
    asm volatile("" ::: "memory");       \
    __builtin_amdgcn_s_barrier();        \
    asm volatile("" ::: "memory");       \
  } while (0)

// ---------------- prep: x fp32->bf16 + all weight transposes ----------------
__global__ __launch_bounds__(256) void k_prep(const float* __restrict__ x,
                                              const float* __restrict__ Wq,
                                              const float* __restrict__ Wk,
                                              const float* __restrict__ Wv,
                                              const float* __restrict__ Wo,
                                              bf16* __restrict__ xb,
                                              bf16* __restrict__ Wqkvt,
                                              bf16* __restrict__ Wot) {
  int id = blockIdx.x;
  int tid = threadIdx.x;
  if (id >= 2560) {  // convert
    size_t base = (size_t)(id - 2560) * 4096 + tid * 16;
#pragma unroll
    for (int j = 0; j < 4; ++j) {
      float4 v = *(const float4*)(x + base + j * 4);
      ushort4 o;
      o.x = __builtin_bit_cast(unsigned short, __float2bfloat16(v.x));
      o.y = __builtin_bit_cast(unsigned short, __float2bfloat16(v.y));
      o.z = __builtin_bit_cast(unsigned short, __float2bfloat16(v.z));
      o.w = __builtin_bit_cast(unsigned short, __float2bfloat16(v.w));
      *(ushort4*)(xb + base + j * 4) = o;
    }
    return;
  }
  const float* W;
  bf16* Wt;
  int N, bx, by;
  if (id < 1024) { W = Wq; Wt = Wqkvt; N = 2048; bx = id & 31; by = id >> 5; }
  else if (id < 1280) { id -= 1024; W = Wk; Wt = Wqkvt + (size_t)2048 * 2048; N = 512; bx = id & 7; by = id >> 3; }
  else if (id < 1536) { id -= 1280; W = Wv; Wt = Wqkvt + (size_t)2560 * 2048; N = 512; bx = id & 7; by = id >> 3; }
  else { id -= 1536; W = Wo; Wt = Wot; N = 2048; bx = id & 31; by = id >> 5; }

  __shared__ float tile[64][65];
  int n0 = bx * 64, k0 = by * 64;
  int tx = tid & 63, tg = tid >> 6;
#pragma unroll
  for (int r = 0; r < 16; ++r) {
    int k = tg * 16 + r;
    tile[k][tx] = W[(size_t)(k0 + k) * N + n0 + tx];
  }
  __syncthreads();
#pragma unroll
  for (int r = 0; r < 16; ++r) {
    int nn = tg * 16 + r;
    Wt[(size_t)(n0 + nn) * 2048 + k0 + tx] = __float2bfloat16(tile[tx][nn]);
  }
}

// ======== 256-row 2-phase/K-tile MFMA GEMM: C = A * Bt^T ========
// BM=256, BK=64, 8 waves (2M x 4N). Phase = M-half x all-N: 8*NR MFMA/phase.
// Double-buffered LDS, XOR swizzle, counted vmcnt (phA: 2+NR, phB: 2).
// EPI: 0 = fp32 C, 1 = bf16 C, 2 = fused qkv epilogue (rope q/k, v->vt^T)
template <int BN, int EPI>
__global__ __launch_bounds__(512, 2) void k_gemm2(const bf16* __restrict__ A,
                                                  const bf16* __restrict__ Bt,
                                                  void* __restrict__ Cout,
                                                  int M, int N, int K,
                                                  const float* __restrict__ cosT,
                                                  const float* __restrict__ sinT,
                                                  bf16* __restrict__ vt) {
  constexpr int NR = BN / 64;  // n-frags per wave == B stage-issues per tile
  __shared__ __align__(16) char As_[2][32768];
  __shared__ __align__(16) char Bs_[2][BN * 128];

  const int tid = threadIdx.x;
  const int w = tid >> 6, lane = tid & 63;
  const int li = lane & 15, g = lane >> 4;
  const int wm = w >> 2, wn = w & 3;

  const int nwg = gridDim.x * gridDim.y;
  int bid = blockIdx.y * gridDim.x + blockIdx.x;
  bid = (bid & 7) * (nwg >> 3) + (bid >> 3);
  const int m0 = (bid / gridDim.x) * 256;
  const int n0 = (bid % gridDim.x) * BN;

  const int ntiles = K >> 6;

  auto sA = [&](int buf, int tile, int half, int issue) {
    if (tile >= ntiles) return;
    const int R0 = half * 64 + issue * 128;
    const int rr = R0 + w * 8 + (lane >> 3);
    const int sl = lane & 7;
    const bf16* src = A + (size_t)(m0 + rr) * K + tile * 64 + ((sl ^ (rr & 7)) * 8);
    gload_lds16(src, As_[buf] + (R0 + w * 8) * 128);
  };
  auto sB = [&](int buf, int tile, int issue) {
    if (tile >= ntiles) return;
    const int block = issue * 8 + w;
    const int rr = block * 8 + (lane >> 3);
    const int sl = lane & 7;
    const bf16* src = Bt + (size_t)(n0 + rr) * K + tile * 64 + ((sl ^ (rr & 7)) * 8);
    gload_lds16(src, Bs_[buf] + block * 1024);
  };

  const int swz0 = (g ^ (li & 7)) * 16;
  const int swz1 = ((4 + g) ^ (li & 7)) * 16;
  bf16x8 af[8], bv[NR * 2];
  f32x4 acc[8][NR] = {};

  auto readA = [&](int buf, int mh) {
#pragma unroll
    for (int m = 0; m < 4; ++m) {
      const char* p = As_[buf] + (wm * 128 + mh * 64 + m * 16 + li) * 128;
      af[m * 2 + 0] = *(const bf16x8*)(p + swz0);
      af[m * 2 + 1] = *(const bf16x8*)(p + swz1);
    }
  };
  auto readB = [&](int buf) {
#pragma unroll
    for (int n = 0; n < NR; ++n) {
      const char* p = Bs_[buf] + (wn * (NR * 16) + n * 16 + li) * 128;
      bv[n * 2 + 0] = *(const bf16x8*)(p + swz0);
      bv[n * 2 + 1] = *(const bf16x8*)(p + swz1);
    }
  };
  auto MMA = [&](int mh) {
    __builtin_amdgcn_s_setprio(1);
#pragma unroll
    for (int m = 0; m < 4; ++m)
#pragma unroll
      for (int n = 0; n < NR; ++n)
#pragma unroll
        for (int kk = 0; kk < 2; ++kk)
          acc[mh * 4 + m][n] = __builtin_amdgcn_mfma_f32_16x16x32_bf16(
              af[m * 2 + kk], bv[n * 2 + kk], acc[mh * 4 + m][n], 0, 0, 0);
    __builtin_amdgcn_s_setprio(0);
  };
  auto VMWA = [&](bool last) {  // covers phB's ds_read (this tile's A1)
    if (last)
      asm volatile("s_waitcnt vmcnt(0)" ::: "memory");
    else if constexpr (NR == 3)
      asm volatile("s_waitcnt vmcnt(5)" ::: "memory");
    else
      asm volatile("s_waitcnt vmcnt(4)" ::: "memory");
    __builtin_amdgcn_sched_barrier(0);
  };
  auto VMWB = [&](bool last) {  // covers next phA's ds_reads (t+1.A0 + t+1.B)
    if (last)
      asm volatile("s_waitcnt vmcnt(0)" ::: "memory");
    else
      asm volatile("s_waitcnt vmcnt(2)" ::: "memory");
    __builtin_amdgcn_sched_barrier(0);
  };

  // ---- prologue: stage tile0 (A0, B, A1); wait A0+B ----
  sA(0, 0, 0, 0); sA(0, 0, 0, 1);
#pragma unroll
  for (int i = 0; i < NR; ++i) sB(0, 0, i);
  sA(0, 0, 1, 0); sA(0, 0, 1, 1);
  asm volatile("s_waitcnt vmcnt(2)" ::: "memory");
  __builtin_amdgcn_sched_barrier(0);
  FBAR();

  for (int t = 0; t < ntiles; ++t) {
    const int cb = t & 1;
    const bool last = (t == ntiles - 1);
    // phA: M-half0 x all N; stage (t+1).A0 + (t+1).B
    readA(cb, 0); readB(cb);
    sA(cb ^ 1, t + 1, 0, 0); sA(cb ^ 1, t + 1, 0, 1);
#pragma unroll
    for (int i = 0; i < NR; ++i) sB(cb ^ 1, t + 1, i);
    VMWA(last);
    FBAR(); MMA(0); FBAR();
    // phB: M-half1; stage (t+1).A1
    readA(cb, 1);
    sA(cb ^ 1, t + 1, 1, 0); sA(cb ^ 1, t + 1, 1, 1);
    VMWB(last);
    FBAR(); MMA(1); FBAR();
  }

  // ---------------- epilogue ----------------
#pragma unroll
  for (int mf = 0; mf < 8; ++mf)
#pragma unroll
    for (int nf = 0; nf < NR; ++nf) {
      const int colc = n0 + wn * (NR * 16) + nf * 16;  // wave-uniform chunk base
      const int col = colc + li;
      const int row0 = m0 + wm * 128 + mf * 16 + g * 4;
      if constexpr (EPI == 2) {
        if (colc < QKS) {  // q or k: rope (q additionally pre-scaled)
          const float qs = (colc < 2048) ? 0.08838834764831845f : 1.0f;
          const int i = (col & 127) >> 1;
          const float sgn = (li & 1) ? 1.0f : -1.0f;
#pragma unroll
          for (int r = 0; r < 4; ++r) {
            const int trow = (row0 + r) & (T_ - 1);
            float v = acc[mf][nf][r];
            float pv = __shfl_xor(v, 1);
            float c = cosT[trow * 64 + i], s = sinT[trow * 64 + i];
            float o = (v * c + pv * (sgn * s)) * qs;
            ((bf16*)Cout)[(size_t)(row0 + r) * QKS + col] = __float2bfloat16(o);
          }
        } else {  // v: write transposed into vt[col-2560][row], 4 rows packed
          unsigned lo = pack_bf2(acc[mf][nf][0], acc[mf][nf][1]);
          unsigned hi = pack_bf2(acc[mf][nf][2], acc[mf][nf][3]);
          uint2 pk = {lo, hi};
          *(uint2*)(vt + (size_t)(col - QKS) * (B_ * T_) + row0) = pk;
        }
      } else {
#pragma unroll
        for (int r = 0; r < 4; ++r) {
          float v = acc[mf][nf][r];
          if constexpr (EPI == 1)
            ((bf16*)Cout)[(size_t)(row0 + r) * N + col] = __float2bfloat16(v);
          else
            ((float*)Cout)[(size_t)(row0 + r) * N + col] = v;
        }
      }
    }
}

// ---------------- windowed flash attention, swapped QK^T ----------------
__global__ __launch_bounds__(512) void k_attn(const bf16* __restrict__ qkv,
                                              const bf16* __restrict__ vt,
                                              bf16* __restrict__ Y) {
  __shared__ __align__(16) char Ks[2][9216];
  __shared__ __align__(16) char Vs[2][10240];
  __shared__ __align__(16) char Pl[8][1280];
  const int lane = threadIdx.x & 63;
  const int w = threadIdx.x >> 6;
  const int li = lane & 15, g = lane >> 4;
  const int t0 = ((int)gridDim.x - 1 - (int)blockIdx.x) * 32;
  const int b = blockIdx.y / NKV, kvh = blockIdx.y % NKV;
  const int h = kvh * 4 + (w >> 1);
  const int qrow0 = t0 + (w & 1) * 16;
  const int t = qrow0 + li;

  bf16x8 qf[4];
  const bf16* qbase = qkv + (size_t)(b * T_ + qrow0 + li) * QKS + h * DH;
#pragma unroll
  for (int dk = 0; dk < 4; ++dk) qf[dk] = *(const bf16x8*)(qbase + dk * 32 + g * 8);

  float mrow = -1e4f;
  float srow = 0.f;
  f32x4 acc[8] = {};

  int ks0 = t0 - (WIN - 1);
  if (ks0 < 0) ks0 = 0;
  ks0 &= ~31;
  const int nt = (t0 + 31 - ks0) / 32 + 1;

  const bf16* kgbase = qkv + (size_t)(b * T_) * QKS + DM + kvh * DH;
  const bf16* vgbase = vt + (size_t)(kvh * DH) * (B_ * T_) + b * T_;

  auto STAGE = [&](int buf, int kt) {
    for (int c = w; c < 19; c += 8) {
      if (c < 9) {
        int slot = c * 64 + lane;
        int row = slot / 17, cc = slot % 17;
        if (slot >= 544) { row = 0; cc = 0; }
        if (cc == 16) cc = 0;
        const bf16* src = kgbase + (size_t)(kt + row) * QKS + cc * 8;
        gload_lds16(src, Ks[buf] + c * 1024);
      } else {
        int c2 = c - 9;
        int slot = c2 * 64 + lane;
        int row = slot / 5, cc = slot % 5;
        if (cc == 4) cc = 0;
        const bf16* src = vgbase + (size_t)row * (B_ * T_) + kt + cc * 8;
        gload_lds16(src, Vs[buf] + c2 * 1024);
      }
    }
  };

  STAGE(0, ks0);
  __syncthreads();
  int cur = 0;

  for (int it = 0; it < nt; ++it) {
    const int kt = ks0 + it * 32;
    if (it + 1 < nt) STAGE(cur ^ 1, kt + 32);

    f32x4 sc[2] = {};
#pragma unroll
    for (int n = 0; n < 2; ++n)
#pragma unroll
      for (int dk = 0; dk < 4; ++dk) {
        bf16x8 kf = *(const bf16x8*)(Ks[cur] + (n * 16 + li) * 272 + dk * 64 + g * 16);
        sc[n] = __builtin_amdgcn_mfma_f32_16x16x32_bf16(kf, qf[dk], sc[n], 0, 0, 0);
      }

    float p[2][4];
    float pmax = -1e30f;
#pragma unroll
    for (int n = 0; n < 2; ++n)
#pragma unroll
      for (int r = 0; r < 4; ++r) {
        int key = kt + n * 16 + g * 4 + r;
        bool valid = (key <= t) && (key > t - WIN);
        float pv = valid ? sc[n][r] : -1e30f;
        p[n][r] = pv;
        pmax = fmaxf(pmax, pv);
      }
    pmax = fmaxf(pmax, __shfl_xor(pmax, 16));
    pmax = fmaxf(pmax, __shfl_xor(pmax, 32));

    // T13 defer-rescale: only rescale when the running max actually grows
    if (!__all(pmax <= mrow)) {
      float nm = fmaxf(mrow, pmax);
      float alpha = __expf(mrow - nm);
      mrow = nm;
      srow *= alpha;
      float af_[4];
#pragma unroll
      for (int r = 0; r < 4; ++r) af_[r] = __shfl(alpha, (g << 2) + r);
#pragma unroll
      for (int db = 0; db < 8; ++db)
#pragma unroll
        for (int r = 0; r < 4; ++r) acc[db][r] *= af_[r];
    }

    float rs = 0.f;
#pragma unroll
    for (int n = 0; n < 2; ++n)
#pragma unroll
      for (int r = 0; r < 4; ++r) {
        p[n][r] = __expf(p[n][r] - mrow);
        rs += p[n][r];
      }
    rs += __shfl_xor(rs, 16);
    rs += __shfl_xor(rs, 32);
    srow += rs;

#pragma unroll
    for (int n = 0; n < 2; ++n) {
      *(unsigned*)(Pl[w] + li * 80 + n * 32 + g * 8) = pack_bf2(p[n][0], p[n][1]);
      *(unsigned*)(Pl[w] + li * 80 + n * 32 + g * 8 + 4) = pack_bf2(p[n][2], p[n][3]);
    }

    bf16x8 pf = *(const bf16x8*)(Pl[w] + li * 80 + g * 16);
#pragma unroll
    for (int db = 0; db < 8; ++db) {
      bf16x8 vf = *(const bf16x8*)(Vs[cur] + (db * 16 + li) * 80 + g * 16);
      acc[db] = __builtin_amdgcn_mfma_f32_16x16x32_bf16(pf, vf, acc[db], 0, 0, 0);
    }

    __syncthreads();
    cur ^= 1;
  }

  float inv[4];
#pragma unroll
  for (int r = 0; r < 4; ++r) inv[r] = 1.f / __shfl(srow, (g << 2) + r);
  bf16* ybase = Y + (size_t)(b * T_ + qrow0 + (g << 2)) * DM + h * DH;
#pragma unroll
  for (int r = 0; r < 4; ++r)
#pragma unroll
    for (int db = 0; db < 8; ++db)
      ybase[(size_t)r * DM + db * 16 + li] = __float2bfloat16(acc[db][r] * inv[r]);
}

extern "C" void kernel_launch(void* const* d_in, const int* in_sizes, int n_in,
                              void* d_out, int out_size, void* d_ws, size_t ws_size,
                              hipStream_t stream) {
  const float* x = (const float*)d_in[0];
  const float* cosT = (const float*)d_in[1];
  const float* sinT = (const float*)d_in[2];
  const float* Wq = (const float*)d_in[3];
  const float* Wk = (const float*)d_in[4];
  const float* Wv = (const float*)d_in[5];
  const float* Wo = (const float*)d_in[6];
  float* out = (float*)d_out;

  char* ws = (char*)d_ws;
  bf16* xb = (bf16*)ws;     ws += (size_t)4096 * 2048 * 2;   // 16.8 MB (reused as yb)
  bf16* Wqkvt = (bf16*)ws;  ws += (size_t)3072 * 2048 * 2;   // 12.6 MB
  bf16* Wot = (bf16*)ws;    ws += (size_t)2048 * 2048 * 2;   // 8.4 MB
  bf16* qkv = (bf16*)ws;    ws += (size_t)4096 * QKS * 2;    // 21.0 MB (q|k only)
  bf16* vt = (bf16*)ws;     ws += (size_t)512 * 4096 * 2;    // 4.2 MB (V^T)
  bf16* yb = xb;

  k_prep<<<4608, 256, 0, stream>>>(x, Wq, Wk, Wv, Wo, xb, Wqkvt, Wot);

  k_gemm2<192, 2><<<dim3(3072 / 192, 4096 / 256), 512, 0, stream>>>(
      xb, Wqkvt, qkv, 4096, 3072, 2048, cosT, sinT, vt);

  k_attn<<<dim3(T_ / 32, B_ * NKV), 512, 0, stream>>>(qkv, vt, yb);

  k_gemm2<128, 0><<<dim3(2048 / 128, 4096 / 256), 512, 0, stream>>>(
      yb, Wot, out, 4096, 2048, 2048, nullptr, nullptr, nullptr);
}